// Round 1
// baseline (1352.451 us; speedup 1.0000x reference)
//
#include <hip/hip_runtime.h>
#include <hip/hip_bf16.h>
#include <math.h>

#define NNODES 100000
#define NEDGES 600000
#define DD 128
#define BM 64
#define LDSX 136   // bf16 row stride for 128-wide tiles (pad 8 -> 2-way-free banks)
#define LDSG 392   // bf16 row stride for 384-wide G tile

typedef __attribute__((ext_vector_type(8))) short bf16x8;
typedef __attribute__((ext_vector_type(4))) float f32x4;
typedef __attribute__((ext_vector_type(4))) unsigned short u16x4;

static __device__ __forceinline__ unsigned short f2bf(float f) {
    unsigned u = __builtin_bit_cast(unsigned, f);
    u += 0x7FFFu + ((u >> 16) & 1u);   // round-to-nearest-even
    return (unsigned short)(u >> 16);
}
static __device__ __forceinline__ float bf2f(unsigned short h) {
    unsigned u = ((unsigned)h) << 16;
    return __builtin_bit_cast(float, u);
}
static __device__ __forceinline__ float gelu_exact(float v) {
    return 0.5f * v * (1.0f + erff(v * 0.7071067811865475f));
}

// ---------------- scatter: S[src] += x[dst], deg[src] += 1 ----------------
__global__ __launch_bounds__(256) void scatter_k(const int* __restrict__ ei,
                                                 const float* __restrict__ x,
                                                 float* __restrict__ S,
                                                 float* __restrict__ deg) {
    int tid = blockIdx.x * 256 + threadIdx.x;
    int e = tid >> 5;
    if (e >= NEDGES) return;
    int lane = tid & 31;
    int s = ei[e];
    int d = ei[NEDGES + e];
    float4 v = *(const float4*)(x + (size_t)d * DD + lane * 4);
    float* dst = S + (size_t)s * DD + lane * 4;
    __hip_atomic_fetch_add(dst + 0, v.x, __ATOMIC_RELAXED, __HIP_MEMORY_SCOPE_AGENT);
    __hip_atomic_fetch_add(dst + 1, v.y, __ATOMIC_RELAXED, __HIP_MEMORY_SCOPE_AGENT);
    __hip_atomic_fetch_add(dst + 2, v.z, __ATOMIC_RELAXED, __HIP_MEMORY_SCOPE_AGENT);
    __hip_atomic_fetch_add(dst + 3, v.w, __ATOMIC_RELAXED, __HIP_MEMORY_SCOPE_AGENT);
    if (lane == 0)
        __hip_atomic_fetch_add(deg + s, 1.0f, __ATOMIC_RELAXED, __HIP_MEMORY_SCOPE_AGENT);
}

// ---------------- fused: all GEMMs + GELU + output GEMM ----------------
// out[v] = gelu(x@Wn.T+bn)@Wu1.T + gelu(S@Wn.T+deg*bn)@Wu2.T
//        + gelu(deg*(x@We1.T)+S@We2.T+deg*be)@Wu3.T + bu
// NOTE: S aliases out (d_out). Each block consumes only its own 64 rows of S
// (staged to LDS up front) and writes only those rows at the end.
__global__ __launch_bounds__(256) void fused_k(const float* __restrict__ x,
                                               const float* __restrict__ S,
                                               const float* __restrict__ deg,
                                               const float* __restrict__ Wn,
                                               const float* __restrict__ bn,
                                               const float* __restrict__ We,
                                               const float* __restrict__ be,
                                               const float* __restrict__ Wu,
                                               const float* __restrict__ bu,
                                               float* __restrict__ out) {
    extern __shared__ char smem_raw[];
    unsigned short* Xs = (unsigned short*)smem_raw;      // [64][136]
    unsigned short* Ss = Xs + BM * LDSX;                 // [64][136]
    unsigned short* Ws = Ss + BM * LDSX;                 // [128][136]
    unsigned short* Gs = Ws + 128 * LDSX;                // [64][392]
    float* degs = (float*)(Gs + BM * LDSG);              // [64]

    const int t = threadIdx.x;
    const int node0 = blockIdx.x * BM;
    const int l = t & 63;
    const int l16 = l & 15;
    const int lk = (l >> 4) << 3;      // 0,8,16,24
    const int rb = (t >> 6) * 16;      // wave's row-tile base
    const int rr = (l >> 4) * 2;       // unused helper avoided; see below

    // ---- stage X and S tiles (f32 -> bf16) + deg ----
    for (int i = t; i < (BM * DD / 4); i += 256) {
        int idx = i << 2;
        int r = idx >> 7, c = idx & 127;
        int gr = node0 + r;
        if (gr >= NNODES) gr = NNODES - 1;   // clamp; garbage rows never stored
        float4 vx = *(const float4*)(x + (size_t)gr * DD + c);
        float4 vs = *(const float4*)(S + (size_t)gr * DD + c);
        u16x4 px = { f2bf(vx.x), f2bf(vx.y), f2bf(vx.z), f2bf(vx.w) };
        u16x4 ps = { f2bf(vs.x), f2bf(vs.y), f2bf(vs.z), f2bf(vs.w) };
        *(u16x4*)(Xs + r * LDSX + c) = px;
        *(u16x4*)(Ss + r * LDSX + c) = ps;
    }
    if (t < BM) {
        int gr = node0 + t;
        degs[t] = (gr < NNODES) ? deg[gr] : 0.0f;
    }

    // weight staging helper: [128 x 128] block of f32 source -> Ws (bf16)
    auto stageW = [&](const float* src, int rs, int co) {
        for (int i = t; i < (128 * DD / 4); i += 256) {
            int idx = i << 2;
            int r = idx >> 7, c = idx & 127;
            float4 v = *(const float4*)(src + (size_t)r * rs + co + c);
            u16x4 pv = { f2bf(v.x), f2bf(v.y), f2bf(v.z), f2bf(v.w) };
            *(u16x4*)(Ws + r * LDSX + c) = pv;
        }
    };
    auto ldA = [&](const unsigned short* base, int stride, int k0) -> bf16x8 {
        return *(const bf16x8*)(base + (rb + l16) * stride + k0 + lk);
    };
    auto ldB = [&](int ct, int k0) -> bf16x8 {
        return *(const bf16x8*)(Ws + (ct * 16 + l16) * LDSX + k0 + lk);
    };

    f32x4 acc1[8], acc2[8], acc3[8];
#pragma unroll
    for (int ct = 0; ct < 8; ++ct) {
        acc1[ct] = {0.f, 0.f, 0.f, 0.f};
        acc2[ct] = {0.f, 0.f, 0.f, 0.f};
        acc3[ct] = {0.f, 0.f, 0.f, 0.f};
    }

    // ---- pair 1: Wn  (x -> acc1, S -> acc2) ----
    __syncthreads();   // staging of X/S/deg done; Ws about to be written
    stageW(Wn, 128, 0);
    __syncthreads();
    float degA = degs[rb + l16];   // deg for A-fragment row (row = lane&15)
#pragma unroll
    for (int kt = 0; kt < 4; ++kt) {
        int k0 = kt * 32;
        bf16x8 aX = ldA(Xs, LDSX, k0);
        bf16x8 aS = ldA(Ss, LDSX, k0);
#pragma unroll
        for (int ct = 0; ct < 8; ++ct) {
            bf16x8 b = ldB(ct, k0);
            acc1[ct] = __builtin_amdgcn_mfma_f32_16x16x32_bf16(aX, b, acc1[ct], 0, 0, 0);
            acc2[ct] = __builtin_amdgcn_mfma_f32_16x16x32_bf16(aS, b, acc2[ct], 0, 0, 0);
        }
    }
    __syncthreads();

    // ---- pair 2: We1 with deg-scaled x -> acc3 ----
    stageW(We, 256, 0);
    __syncthreads();
#pragma unroll
    for (int kt = 0; kt < 4; ++kt) {
        int k0 = kt * 32;
        bf16x8 aX = ldA(Xs, LDSX, k0);
        bf16x8 aXd;
#pragma unroll
        for (int j = 0; j < 8; ++j)
            aXd[j] = (short)f2bf(bf2f((unsigned short)aX[j]) * degA);
#pragma unroll
        for (int ct = 0; ct < 8; ++ct) {
            bf16x8 b = ldB(ct, k0);
            acc3[ct] = __builtin_amdgcn_mfma_f32_16x16x32_bf16(aXd, b, acc3[ct], 0, 0, 0);
        }
    }
    __syncthreads();

    // ---- pair 3: We2 with S -> acc3 ----
    stageW(We, 256, 128);
    __syncthreads();
#pragma unroll
    for (int kt = 0; kt < 4; ++kt) {
        int k0 = kt * 32;
        bf16x8 aS = ldA(Ss, LDSX, k0);
#pragma unroll
        for (int ct = 0; ct < 8; ++ct) {
            bf16x8 b = ldB(ct, k0);
            acc3[ct] = __builtin_amdgcn_mfma_f32_16x16x32_bf16(aS, b, acc3[ct], 0, 0, 0);
        }
    }
    __syncthreads();

    // ---- epilogue phase 1: biases + GELU -> Gs (bf16) ----
#pragma unroll
    for (int ct = 0; ct < 8; ++ct) {
        int col = ct * 16 + l16;
        float bnc = bn[col];
        float bec = be[col];
#pragma unroll
        for (int r = 0; r < 4; ++r) {
            int row = rb + (l >> 4) * 4 + r;
            float dg = degs[row];
            Gs[row * LDSG + col]       = f2bf(gelu_exact(acc1[ct][r] + bnc));
            Gs[row * LDSG + 128 + col] = f2bf(gelu_exact(acc2[ct][r] + dg * bnc));
            Gs[row * LDSG + 256 + col] = f2bf(gelu_exact(acc3[ct][r] + dg * bec));
        }
    }
    __syncthreads();

    // ---- phase 2: out = gelu(pre) @ Wu.T + bu ----
    f32x4 accO[8];
#pragma unroll
    for (int ct = 0; ct < 8; ++ct) accO[ct] = {0.f, 0.f, 0.f, 0.f};

    for (int kc = 0; kc < 3; ++kc) {
        stageW(Wu, 384, kc * 128);
        __syncthreads();
#pragma unroll
        for (int kt = 0; kt < 4; ++kt) {
            int k0 = kt * 32;
            bf16x8 aG = *(const bf16x8*)(Gs + (rb + l16) * LDSG + kc * 128 + k0 + lk);
#pragma unroll
            for (int ct = 0; ct < 8; ++ct) {
                bf16x8 b = ldB(ct, k0);
                accO[ct] = __builtin_amdgcn_mfma_f32_16x16x32_bf16(aG, b, accO[ct], 0, 0, 0);
            }
        }
        __syncthreads();
    }

    // ---- store (overwrites the S rows this block owns) ----
#pragma unroll
    for (int ct = 0; ct < 8; ++ct) {
        int col = ct * 16 + l16;
        float buc = bu[col];
#pragma unroll
        for (int r = 0; r < 4; ++r) {
            int grow = node0 + rb + (l >> 4) * 4 + r;
            if (grow < NNODES)
                out[(size_t)grow * DD + col] = accO[ct][r] + buc;
        }
    }
}

extern "C" void kernel_launch(void* const* d_in, const int* in_sizes, int n_in,
                              void* d_out, int out_size, void* d_ws, size_t ws_size,
                              hipStream_t stream) {
    const float* x  = (const float*)d_in[0];
    const int*   ei = (const int*)d_in[1];
    const float* Wn = (const float*)d_in[2];
    const float* bn = (const float*)d_in[3];
    const float* We = (const float*)d_in[4];
    const float* be = (const float*)d_in[5];
    const float* Wu = (const float*)d_in[6];
    const float* bu = (const float*)d_in[7];

    float* out = (float*)d_out;
    float* S   = out;              // alias: S lives in d_out until overwritten
    float* deg = (float*)d_ws;     // NNODES floats of scratch

    hipMemsetAsync(S, 0, (size_t)NNODES * DD * sizeof(float), stream);
    hipMemsetAsync(deg, 0, (size_t)NNODES * sizeof(float), stream);

    int sblocks = (NEDGES * 32) / 256;   // 75000
    scatter_k<<<sblocks, 256, 0, stream>>>(ei, x, S, deg);

    int fblocks = (NNODES + BM - 1) / BM;  // 1563
    size_t lds_bytes = (size_t)(BM * LDSX + BM * LDSX + 128 * LDSX + BM * LDSG) * 2
                     + BM * sizeof(float);  // 120,064 B
    fused_k<<<fblocks, 256, lds_bytes, stream>>>(x, S, deg, Wn, bn, We, be, Wu, bu, out);
}

// Round 2
// 292.031 us; speedup vs baseline: 4.6312x; 4.6312x over previous
//
#include <hip/hip_runtime.h>
#include <hip/hip_bf16.h>
#include <math.h>

#define NNODES 100000
#define NEDGES 600000
#define DD 128
#define BM 64
#define LDSX 136   // bf16 row stride (272B = 17*16 -> keeps b128 16B-aligned, banks spread)
#define SCAN_B 512

typedef __attribute__((ext_vector_type(8))) short bf16x8;
typedef __attribute__((ext_vector_type(4))) float f32x4;
typedef __attribute__((ext_vector_type(4))) unsigned short u16x4;

static __device__ __forceinline__ unsigned short f2bf(float f) {
    unsigned u = __builtin_bit_cast(unsigned, f);
    u += 0x7FFFu + ((u >> 16) & 1u);   // round-to-nearest-even
    return (unsigned short)(u >> 16);
}
static __device__ __forceinline__ float bf2f(unsigned short h) {
    unsigned u = ((unsigned)h) << 16;
    return __builtin_bit_cast(float, u);
}
static __device__ __forceinline__ float gelu_exact(float v) {
    return 0.5f * v * (1.0f + erff(v * 0.7071067811865475f));
}

// ---------------- weight pre-convert: f32 -> bf16, [Wn|We|Wu] packed ----------------
__global__ __launch_bounds__(256) void cvtw_k(const float* __restrict__ Wn,
                                              const float* __restrict__ We,
                                              const float* __restrict__ Wu,
                                              unsigned short* __restrict__ wbf) {
    int i = blockIdx.x * 256 + threadIdx.x;
    float v;
    if (i < 16384) v = Wn[i];
    else if (i < 49152) v = We[i - 16384];
    else if (i < 98304) v = Wu[i - 49152];
    else return;
    wbf[i] = f2bf(v);
}

// ---------------- CSR build ----------------
__global__ __launch_bounds__(256) void hist_k(const int* __restrict__ ei, int* __restrict__ cnt) {
    int e = blockIdx.x * 256 + threadIdx.x;
    if (e < NEDGES) atomicAdd(&cnt[ei[e]], 1);
}

__global__ __launch_bounds__(SCAN_B) void scan_local(const int* __restrict__ cnt,
                                                     int* __restrict__ off,
                                                     int* __restrict__ bsum) {
    __shared__ int sh[SCAN_B];
    int i = blockIdx.x * SCAN_B + threadIdx.x;
    int v = (i < NNODES) ? cnt[i] : 0;
    sh[threadIdx.x] = v;
    __syncthreads();
    for (int d = 1; d < SCAN_B; d <<= 1) {
        int t = (threadIdx.x >= d) ? sh[threadIdx.x - d] : 0;
        __syncthreads();
        sh[threadIdx.x] += t;
        __syncthreads();
    }
    if (i < NNODES) off[i] = sh[threadIdx.x] - v;    // exclusive
    if (threadIdx.x == SCAN_B - 1) bsum[blockIdx.x] = sh[threadIdx.x];
}

__global__ __launch_bounds__(SCAN_B) void scan_bsum(int* __restrict__ bsum, int nb) {
    __shared__ int sh[SCAN_B];
    int v = (threadIdx.x < nb) ? bsum[threadIdx.x] : 0;
    sh[threadIdx.x] = v;
    __syncthreads();
    for (int d = 1; d < SCAN_B; d <<= 1) {
        int t = (threadIdx.x >= d) ? sh[threadIdx.x - d] : 0;
        __syncthreads();
        sh[threadIdx.x] += t;
        __syncthreads();
    }
    if (threadIdx.x < nb) bsum[threadIdx.x] = sh[threadIdx.x] - v;   // exclusive
}

__global__ __launch_bounds__(256) void scan_add(int* __restrict__ off,
                                                const int* __restrict__ bsum,
                                                const int* __restrict__ cnt,
                                                float* __restrict__ degf) {
    int i = blockIdx.x * 256 + threadIdx.x;
    if (i < NNODES) {
        off[i] += bsum[i / SCAN_B];
        degf[i] = (float)cnt[i];
    }
}

__global__ __launch_bounds__(256) void fill_k(const int* __restrict__ ei,
                                              int* __restrict__ off,
                                              int* __restrict__ edst) {
    int e = blockIdx.x * 256 + threadIdx.x;
    if (e >= NEDGES) return;
    int s = ei[e], d = ei[NEDGES + e];
    int pos = atomicAdd(&off[s], 1);
    edst[pos] = d;
}

// ---------------- aggregate: S[v] = sum over edges(src=v) of x[dst] ----------------
__global__ __launch_bounds__(256) void agg_k(const int* __restrict__ off,
                                             const int* __restrict__ edst,
                                             const float* __restrict__ x,
                                             float* __restrict__ S) {
    int node = (blockIdx.x * 256 + threadIdx.x) >> 6;
    if (node >= NNODES) return;
    int lane = threadIdx.x & 63;
    int end = off[node];
    int beg = (node > 0) ? off[node - 1] : 0;
    float ax0 = 0.f, ay0 = 0.f, ax1 = 0.f, ay1 = 0.f;
    int e = beg;
    for (; e + 1 < end; e += 2) {
        int d0 = edst[e], d1 = edst[e + 1];
        float2 v0 = *(const float2*)(x + (size_t)d0 * DD + lane * 2);
        float2 v1 = *(const float2*)(x + (size_t)d1 * DD + lane * 2);
        ax0 += v0.x; ay0 += v0.y;
        ax1 += v1.x; ay1 += v1.y;
    }
    if (e < end) {
        int d0 = edst[e];
        float2 v0 = *(const float2*)(x + (size_t)d0 * DD + lane * 2);
        ax0 += v0.x; ay0 += v0.y;
    }
    float2 r = { ax0 + ax1, ay0 + ay1 };
    *(float2*)(S + (size_t)node * DD + lane * 2) = r;
}

// ---------------- fallback scatter (atomics) if ws too small ----------------
__global__ __launch_bounds__(256) void scatter_k(const int* __restrict__ ei,
                                                 const float* __restrict__ x,
                                                 float* __restrict__ S,
                                                 float* __restrict__ deg) {
    int tid = blockIdx.x * 256 + threadIdx.x;
    int e = tid >> 5;
    if (e >= NEDGES) return;
    int lane = tid & 31;
    int s = ei[e];
    int d = ei[NEDGES + e];
    float4 v = *(const float4*)(x + (size_t)d * DD + lane * 4);
    float* dst = S + (size_t)s * DD + lane * 4;
    __hip_atomic_fetch_add(dst + 0, v.x, __ATOMIC_RELAXED, __HIP_MEMORY_SCOPE_AGENT);
    __hip_atomic_fetch_add(dst + 1, v.y, __ATOMIC_RELAXED, __HIP_MEMORY_SCOPE_AGENT);
    __hip_atomic_fetch_add(dst + 2, v.z, __ATOMIC_RELAXED, __HIP_MEMORY_SCOPE_AGENT);
    __hip_atomic_fetch_add(dst + 3, v.w, __ATOMIC_RELAXED, __HIP_MEMORY_SCOPE_AGENT);
    if (lane == 0)
        __hip_atomic_fetch_add(deg + s, 1.0f, __ATOMIC_RELAXED, __HIP_MEMORY_SCOPE_AGENT);
}

// ---------------- fused: 7 GEMMs + GELU, 69.9KB LDS -> 2 blocks/CU ----------------
// out[v] = gelu(x@Wn.T+bn)@Wu0.T + gelu(S@Wn.T+deg*bn)@Wu1.T
//        + gelu(deg*(x@We1.T)+S@We2.T+deg*be)@Wu2.T + bu
// S aliases out; each block stages its own 64 S-rows before any out-store.
template <bool PREBF>
__global__ __launch_bounds__(256, 2) void fused_k(const float* __restrict__ x,
                                                  const float* __restrict__ S,
                                                  const float* __restrict__ degf,
                                                  const float* __restrict__ Wn,
                                                  const float* __restrict__ We,
                                                  const float* __restrict__ Wu,
                                                  const unsigned short* __restrict__ wbf,
                                                  const float* __restrict__ bn,
                                                  const float* __restrict__ be,
                                                  const float* __restrict__ bu,
                                                  float* __restrict__ out) {
    extern __shared__ char smem_raw[];
    unsigned short* Xs = (unsigned short*)smem_raw;      // [64][136]  (X, later S)
    unsigned short* Ws = Xs + BM * LDSX;                 // [128][136]
    unsigned short* Gs = Ws + 128 * LDSX;                // [64][136]
    float* degs = (float*)(Gs + BM * LDSX);              // [64]

    const int t = threadIdx.x;
    const int node0 = blockIdx.x * BM;
    const int l = t & 63;
    const int l16 = l & 15;
    const int lk = (l >> 4) << 3;
    const int rb = (t >> 6) * 16;

    auto stageX = [&](const float* src) {
        for (int i = t; i < (BM * DD / 4); i += 256) {
            int idx = i << 2;
            int r = idx >> 7, c = idx & 127;
            int gr = node0 + r;
            if (gr >= NNODES) gr = NNODES - 1;
            float4 v = *(const float4*)(src + (size_t)gr * DD + c);
            u16x4 p = { f2bf(v.x), f2bf(v.y), f2bf(v.z), f2bf(v.w) };
            *(u16x4*)(Xs + r * LDSX + c) = p;
        }
    };
    auto stageW = [&](const float* srcf, const unsigned short* srcb, int rs, int co) {
        if constexpr (PREBF) {
            for (int i = t; i < (128 * DD / 8); i += 256) {
                int idx = i << 3;
                int r = idx >> 7, c = idx & 127;
                *(bf16x8*)(Ws + r * LDSX + c) = *(const bf16x8*)(srcb + (size_t)r * rs + co + c);
            }
        } else {
            for (int i = t; i < (128 * DD / 4); i += 256) {
                int idx = i << 2;
                int r = idx >> 7, c = idx & 127;
                float4 v = *(const float4*)(srcf + (size_t)r * rs + co + c);
                u16x4 p = { f2bf(v.x), f2bf(v.y), f2bf(v.z), f2bf(v.w) };
                *(u16x4*)(Ws + r * LDSX + c) = p;
            }
        }
    };
    auto run_gemm = [&](const unsigned short* A, f32x4* acc, const float* scale) {
#pragma unroll
        for (int kt = 0; kt < 4; ++kt) {
            int k0 = kt * 32;
            bf16x8 a = *(const bf16x8*)(A + (rb + l16) * LDSX + k0 + lk);
            if (scale) {
#pragma unroll
                for (int j = 0; j < 8; ++j)
                    a[j] = (short)f2bf(bf2f((unsigned short)a[j]) * (*scale));
            }
#pragma unroll
            for (int ct = 0; ct < 8; ++ct) {
                bf16x8 b = *(const bf16x8*)(Ws + (ct * 16 + l16) * LDSX + k0 + lk);
                acc[ct] = __builtin_amdgcn_mfma_f32_16x16x32_bf16(a, b, acc[ct], 0, 0, 0);
            }
        }
    };
    auto gelu_to_Gs = [&](f32x4* acc, const float* bias, bool useDeg) {
#pragma unroll
        for (int ct = 0; ct < 8; ++ct) {
            int col = ct * 16 + l16;
            float bc = bias[col];
#pragma unroll
            for (int r = 0; r < 4; ++r) {
                int row = rb + ((l >> 4) << 2) + r;
                float v = acc[ct][r] + (useDeg ? degs[row] * bc : bc);
                Gs[row * LDSX + col] = f2bf(gelu_exact(v));
            }
        }
    };

    const unsigned short* WnB = wbf;
    const unsigned short* WeB = wbf + 16384;
    const unsigned short* WuB = wbf + 49152;

    f32x4 acc1[8], acc3[8], accO[8];
#pragma unroll
    for (int ct = 0; ct < 8; ++ct) {
        acc1[ct] = {0.f, 0.f, 0.f, 0.f};
        acc3[ct] = {0.f, 0.f, 0.f, 0.f};
        accO[ct] = {0.f, 0.f, 0.f, 0.f};
    }

    // phase 0: stage X, deg, Wn
    stageX(x);
    if (t < BM) {
        int gr = node0 + t;
        degs[t] = (gr < NNODES) ? degf[gr] : 0.0f;
    }
    stageW(Wn, WnB, 128, 0);
    __syncthreads();
    float degA = degs[rb + l16];

    run_gemm(Xs, acc1, nullptr);            // x @ Wn.T
    __syncthreads();
    stageW(We, WeB, 256, 0);                // We1
    __syncthreads();
    run_gemm(Xs, acc3, &degA);              // deg*x @ We1.T
    __syncthreads();

    // chunk0 epilogue + begin Wu0, swap Xs -> S
    gelu_to_Gs(acc1, bn, false);
    stageW(Wu, WuB, 384, 0);
    stageX(S);
    __syncthreads();
    run_gemm(Gs, accO, nullptr);            // g0 @ Wu0.T
    __syncthreads();

    stageW(Wn, WnB, 128, 0);                // Wn again (cheap, L2/bf16)
    __syncthreads();
    f32x4 acc2[8];
#pragma unroll
    for (int ct = 0; ct < 8; ++ct) acc2[ct] = {0.f, 0.f, 0.f, 0.f};
    run_gemm(Xs, acc2, nullptr);            // S @ Wn.T
    __syncthreads();
    stageW(We, WeB, 256, 128);              // We2
    __syncthreads();
    run_gemm(Xs, acc3, nullptr);            // += S @ We2.T
    __syncthreads();

    gelu_to_Gs(acc2, bn, true);             // g1 = gelu(S@Wn.T + deg*bn)
    stageW(Wu, WuB, 384, 128);
    __syncthreads();
    run_gemm(Gs, accO, nullptr);            // += g1 @ Wu1.T
    __syncthreads();

    gelu_to_Gs(acc3, be, true);             // g2 = gelu(... + deg*be)
    stageW(Wu, WuB, 384, 256);
    __syncthreads();
    run_gemm(Gs, accO, nullptr);            // += g2 @ Wu2.T

    // store
#pragma unroll
    for (int ct = 0; ct < 8; ++ct) {
        int col = ct * 16 + l16;
        float buc = bu[col];
#pragma unroll
        for (int r = 0; r < 4; ++r) {
            int grow = node0 + rb + ((l >> 4) << 2) + r;
            if (grow < NNODES)
                out[(size_t)grow * DD + col] = accO[ct][r] + buc;
        }
    }
}

extern "C" void kernel_launch(void* const* d_in, const int* in_sizes, int n_in,
                              void* d_out, int out_size, void* d_ws, size_t ws_size,
                              hipStream_t stream) {
    const float* x  = (const float*)d_in[0];
    const int*   ei = (const int*)d_in[1];
    const float* Wn = (const float*)d_in[2];
    const float* bn = (const float*)d_in[3];
    const float* We = (const float*)d_in[4];
    const float* be = (const float*)d_in[5];
    const float* Wu = (const float*)d_in[6];
    const float* bu = (const float*)d_in[7];

    float* out = (float*)d_out;
    float* S   = out;   // alias: S lives in d_out until each block overwrites its rows

    size_t lds_bytes = (size_t)(BM * LDSX + 128 * LDSX + BM * LDSX) * 2 + BM * sizeof(float);
    int fblocks = (NNODES + BM - 1) / BM;   // 1563

    // ws layout (CSR path): wbf[98304 u16] | degf[N f32] | cnt[N i32] | off[N i32] | bsum[512 i32] | edst[E i32]
    size_t need = 98304 * 2 + (size_t)NNODES * 4 * 3 + 512 * 4 + (size_t)NEDGES * 4;  // 3,798,656

    if (ws_size >= need) {
        unsigned short* wbf = (unsigned short*)d_ws;
        float* degf = (float*)(wbf + 98304);
        int* cnt  = (int*)(degf + NNODES);
        int* off  = cnt + NNODES;
        int* bsum = off + NNODES;
        int* edst = bsum + 512;

        cvtw_k<<<384, 256, 0, stream>>>(Wn, We, Wu, wbf);
        hipMemsetAsync(cnt, 0, (size_t)NNODES * sizeof(int), stream);
        hist_k<<<(NEDGES + 255) / 256, 256, 0, stream>>>(ei, cnt);
        int nb = (NNODES + SCAN_B - 1) / SCAN_B;  // 196
        scan_local<<<nb, SCAN_B, 0, stream>>>(cnt, off, bsum);
        scan_bsum<<<1, SCAN_B, 0, stream>>>(bsum, nb);
        scan_add<<<(NNODES + 255) / 256, 256, 0, stream>>>(off, bsum, cnt, degf);
        fill_k<<<(NEDGES + 255) / 256, 256, 0, stream>>>(ei, off, edst);
        agg_k<<<NNODES / 4, 256, 0, stream>>>(off, edst, x, S);
        fused_k<true><<<fblocks, 256, lds_bytes, stream>>>(x, S, degf, Wn, We, Wu, wbf,
                                                           bn, be, bu, out);
    } else {
        // fallback: atomic scatter (proven path), f32 weights staged in-kernel
        float* degf = (float*)d_ws;
        hipMemsetAsync(S, 0, (size_t)NNODES * DD * sizeof(float), stream);
        hipMemsetAsync(degf, 0, (size_t)NNODES * sizeof(float), stream);
        scatter_k<<<(NEDGES * 32) / 256, 256, 0, stream>>>(ei, x, S, degf);
        fused_k<false><<<fblocks, 256, lds_bytes, stream>>>(x, S, degf, Wn, We, Wu, nullptr,
                                                            bn, be, bu, out);
    }
}

// Round 3
// 238.977 us; speedup vs baseline: 5.6593x; 1.2220x over previous
//
#include <hip/hip_runtime.h>
#include <hip/hip_bf16.h>
#include <math.h>

#define NNODES 100000
#define NEDGES 600000
#define DD 128
#define SCAN_B 512

typedef __attribute__((ext_vector_type(8))) short bf16x8;
typedef __attribute__((ext_vector_type(4))) float f32x4;

template <int N> struct Int { static constexpr int value = N; };

static __device__ __forceinline__ unsigned short f2bf(float f) {
    unsigned u = __builtin_bit_cast(unsigned, f);
    u += 0x7FFFu + ((u >> 16) & 1u);   // RNE
    return (unsigned short)(u >> 16);
}
static __device__ __forceinline__ float bf2f(unsigned short h) {
    unsigned u = ((unsigned)h) << 16;
    return __builtin_bit_cast(float, u);
}
static __device__ __forceinline__ float gelu_exact(float v) {
    return 0.5f * v * (1.0f + erff(v * 0.7071067811865475f));
}

#if __has_builtin(__builtin_amdgcn_global_load_lds)
#define HAVE_GLDS 1
#else
#define HAVE_GLDS 0
#endif

static __device__ __forceinline__ void gload_lds16(const unsigned short* g, unsigned short* s, int lane) {
#if HAVE_GLDS
    (void)lane;
    __builtin_amdgcn_global_load_lds((const __attribute__((address_space(1))) void*)g,
                                     (__attribute__((address_space(3))) void*)s, 16, 0, 0);
#else
    *(bf16x8*)(s + lane * 8) = *(const bf16x8*)g;   // slow-but-correct fallback
#endif
}

#define MFMA(a, b, c) __builtin_amdgcn_mfma_f32_16x16x32_bf16(a, b, c, 0, 0, 0)
#define BARX() do { asm volatile("s_waitcnt lgkmcnt(0)" ::: "memory"); \
                    __builtin_amdgcn_s_barrier(); } while (0)
#define HALF_PRE(h) do { \
    if ((h) == 11) asm volatile("s_waitcnt vmcnt(0)" ::: "memory"); \
    else           asm volatile("s_waitcnt vmcnt(4)" ::: "memory"); \
    asm volatile("s_waitcnt lgkmcnt(0)" ::: "memory"); \
    __builtin_amdgcn_s_barrier(); \
    if ((h) + 2 < 12) issue_half((h) + 2); } while (0)

// ---------------- x f32 -> bf16 ----------------
__global__ __launch_bounds__(256) void cvtx_k(const float* __restrict__ x,
                                              unsigned short* __restrict__ xb) {
    int i = blockIdx.x * 256 + threadIdx.x;
    if (i >= NNODES * DD / 8) return;
    float4 v0 = *(const float4*)(x + (size_t)i * 8);
    float4 v1 = *(const float4*)(x + (size_t)i * 8 + 4);
    unsigned short o[8] = { f2bf(v0.x), f2bf(v0.y), f2bf(v0.z), f2bf(v0.w),
                            f2bf(v1.x), f2bf(v1.y), f2bf(v1.z), f2bf(v1.w) };
    *(bf16x8*)(xb + (size_t)i * 8) = *(bf16x8*)o;
}

// ------- weights -> fragment-major bf16: [tile][kt][ct][lane][8], tiles in
// phase order [Wn, Wu0, We1, We2, Wu1, Wu2] -------
__global__ __launch_bounds__(256) void cvtw2_k(const float* __restrict__ Wn,
                                               const float* __restrict__ We,
                                               const float* __restrict__ Wu,
                                               unsigned short* __restrict__ wfrag) {
    int tid = blockIdx.x * 256 + threadIdx.x;
    if (tid >= 6 * 4 * 8 * 64) return;
    int l = tid & 63;
    int ct = (tid >> 6) & 7;
    int kt = (tid >> 9) & 3;
    int tile = tid >> 11;
    int n = ct * 16 + (l & 15);
    int k = kt * 32 + (l >> 4) * 8;
    const float* src;
    switch (tile) {
        case 0:  src = Wn + (size_t)n * 128 + k;        break;  // Wn
        case 1:  src = Wu + (size_t)n * 384 + k;        break;  // Wu0
        case 2:  src = We + (size_t)n * 256 + k;        break;  // We1
        case 3:  src = We + (size_t)n * 256 + 128 + k;  break;  // We2
        case 4:  src = Wu + (size_t)n * 384 + 128 + k;  break;  // Wu1
        default: src = Wu + (size_t)n * 384 + 256 + k;  break;  // Wu2
    }
    unsigned short o[8];
#pragma unroll
    for (int j = 0; j < 8; ++j) o[j] = f2bf(src[j]);
    *(bf16x8*)(wfrag + (size_t)tid * 8) = *(bf16x8*)o;
}

// ---------------- CSR build ----------------
__global__ __launch_bounds__(256) void hist_k(const int* __restrict__ ei, int* __restrict__ cnt) {
    int e = blockIdx.x * 256 + threadIdx.x;
    if (e < NEDGES) atomicAdd(&cnt[ei[e]], 1);
}

__global__ __launch_bounds__(SCAN_B) void scan_local(const int* __restrict__ cnt,
                                                     int* __restrict__ off,
                                                     int* __restrict__ bsum) {
    __shared__ int sh[SCAN_B];
    int i = blockIdx.x * SCAN_B + threadIdx.x;
    int v = (i < NNODES) ? cnt[i] : 0;
    sh[threadIdx.x] = v;
    __syncthreads();
    for (int d = 1; d < SCAN_B; d <<= 1) {
        int t = (threadIdx.x >= d) ? sh[threadIdx.x - d] : 0;
        __syncthreads();
        sh[threadIdx.x] += t;
        __syncthreads();
    }
    if (i < NNODES) off[i] = sh[threadIdx.x] - v;
    if (threadIdx.x == SCAN_B - 1) bsum[blockIdx.x] = sh[threadIdx.x];
}

__global__ __launch_bounds__(SCAN_B) void scan_bsum(int* __restrict__ bsum, int nb) {
    __shared__ int sh[SCAN_B];
    int v = (threadIdx.x < nb) ? bsum[threadIdx.x] : 0;
    sh[threadIdx.x] = v;
    __syncthreads();
    for (int d = 1; d < SCAN_B; d <<= 1) {
        int t = (threadIdx.x >= d) ? sh[threadIdx.x - d] : 0;
        __syncthreads();
        sh[threadIdx.x] += t;
        __syncthreads();
    }
    if (threadIdx.x < nb) bsum[threadIdx.x] = sh[threadIdx.x] - v;
}

__global__ __launch_bounds__(256) void scan_add(int* __restrict__ off,
                                                const int* __restrict__ bsum,
                                                const int* __restrict__ cnt,
                                                float* __restrict__ degf) {
    int i = blockIdx.x * 256 + threadIdx.x;
    if (i < NNODES) {
        off[i] += bsum[i / SCAN_B];
        degf[i] = (float)cnt[i];
    }
}

__global__ __launch_bounds__(256) void fill_k(const int* __restrict__ ei,
                                              int* __restrict__ off,
                                              int* __restrict__ edst) {
    int e = blockIdx.x * 256 + threadIdx.x;
    if (e >= NEDGES) return;
    int s = ei[e], d = ei[NEDGES + e];
    int pos = atomicAdd(&off[s], 1);
    edst[pos] = d;
}

// ------- aggregate S[v] = sum x[dst], bf16-x variant -------
__global__ __launch_bounds__(256) void agg_bf_k(const int* __restrict__ off,
                                                const int* __restrict__ edst,
                                                const unsigned short* __restrict__ xb,
                                                float* __restrict__ S) {
    int node = (blockIdx.x * 256 + threadIdx.x) >> 6;
    if (node >= NNODES) return;
    int lane = threadIdx.x & 63;
    int end = off[node];
    int beg = node ? off[node - 1] : 0;
    float a0 = 0.f, a1 = 0.f, b0 = 0.f, b1 = 0.f;
    int e = beg;
    for (; e + 1 < end; e += 2) {
        unsigned v0 = *(const unsigned*)(xb + (size_t)edst[e] * DD + lane * 2);
        unsigned v1 = *(const unsigned*)(xb + (size_t)edst[e + 1] * DD + lane * 2);
        a0 += bf2f((unsigned short)(v0 & 0xffff)); a1 += bf2f((unsigned short)(v0 >> 16));
        b0 += bf2f((unsigned short)(v1 & 0xffff)); b1 += bf2f((unsigned short)(v1 >> 16));
    }
    if (e < end) {
        unsigned v0 = *(const unsigned*)(xb + (size_t)edst[e] * DD + lane * 2);
        a0 += bf2f((unsigned short)(v0 & 0xffff)); a1 += bf2f((unsigned short)(v0 >> 16));
    }
    float2 r = { a0 + b0, a1 + b1 };
    *(float2*)(S + (size_t)node * DD + lane * 2) = r;
}

// ------- f32-x variant (fallback when ws too small for xb) -------
__global__ __launch_bounds__(256) void agg_k(const int* __restrict__ off,
                                             const int* __restrict__ edst,
                                             const float* __restrict__ x,
                                             float* __restrict__ S) {
    int node = (blockIdx.x * 256 + threadIdx.x) >> 6;
    if (node >= NNODES) return;
    int lane = threadIdx.x & 63;
    int end = off[node];
    int beg = node ? off[node - 1] : 0;
    float ax0 = 0.f, ay0 = 0.f, ax1 = 0.f, ay1 = 0.f;
    int e = beg;
    for (; e + 1 < end; e += 2) {
        float2 v0 = *(const float2*)(x + (size_t)edst[e] * DD + lane * 2);
        float2 v1 = *(const float2*)(x + (size_t)edst[e + 1] * DD + lane * 2);
        ax0 += v0.x; ay0 += v0.y;
        ax1 += v1.x; ay1 += v1.y;
    }
    if (e < end) {
        float2 v0 = *(const float2*)(x + (size_t)edst[e] * DD + lane * 2);
        ax0 += v0.x; ay0 += v0.y;
    }
    float2 r = { ax0 + ax1, ay0 + ay1 };
    *(float2*)(S + (size_t)node * DD + lane * 2) = r;
}

// ---------------- fused GEMMs: pipelined, frag-major weights ----------------
// out[v] = gelu(x@Wn.T+bn)@Wu0.T + gelu(S@Wn.T+deg*bn)@Wu1.T
//        + gelu(deg*(x@We1.T)+S@We2.T+deg*be)@Wu2.T + bu
// S aliases out: each block reads only its 64 rows (at kernel start, into regs)
// and writes only those rows at the end.
template <bool XBF>
__global__ __launch_bounds__(256, 2) void fused2_k(const float* __restrict__ xf,
                                                   const unsigned short* __restrict__ xb,
                                                   const float* __restrict__ S,
                                                   const float* __restrict__ degf,
                                                   const unsigned short* __restrict__ wfrag,
                                                   const float* __restrict__ bn,
                                                   const float* __restrict__ be,
                                                   const float* __restrict__ bu,
                                                   float* __restrict__ out) {
    extern __shared__ char smem[];
    unsigned short* H  = (unsigned short*)smem;      // 3 x 8192 u16 (16KB halves)
    unsigned short* Gs = H + 3 * 8192;               // [64][136] u16
    float* degs = (float*)(Gs + 64 * 136);           // [64]

    const int t = threadIdx.x;
    const int w = t >> 6;
    const int l = t & 63;
    const int wc = w & 1;            // col-wave: ct in [wc*4, wc*4+4)
    const int rb = (w >> 1) * 32;    // row base within 64-tile
    const int l16 = l & 15;
    const int lg = l >> 4;
    const int node0 = blockIdx.x * 64;

    int r0 = node0 + rb + l16;      if (r0 > NNODES - 1) r0 = NNODES - 1;
    int r1 = node0 + rb + 16 + l16; if (r1 > NNODES - 1) r1 = NNODES - 1;

    // ---- A fragments into registers ----
    bf16x8 aX[4][2], aS[4][2];
    if constexpr (XBF) {
        const unsigned short* x0 = xb + (size_t)r0 * DD;
        const unsigned short* x1 = xb + (size_t)r1 * DD;
#pragma unroll
        for (int kt = 0; kt < 4; ++kt) {
            aX[kt][0] = *(const bf16x8*)(x0 + kt * 32 + lg * 8);
            aX[kt][1] = *(const bf16x8*)(x1 + kt * 32 + lg * 8);
        }
    } else {
        const float* x0 = xf + (size_t)r0 * DD;
        const float* x1 = xf + (size_t)r1 * DD;
#pragma unroll
        for (int kt = 0; kt < 4; ++kt)
#pragma unroll
            for (int f = 0; f < 2; ++f) {
                const float* p = (f ? x1 : x0) + kt * 32 + lg * 8;
                float4 v0 = *(const float4*)(p);
                float4 v1 = *(const float4*)(p + 4);
                bf16x8 a;
                a[0] = (short)f2bf(v0.x); a[1] = (short)f2bf(v0.y);
                a[2] = (short)f2bf(v0.z); a[3] = (short)f2bf(v0.w);
                a[4] = (short)f2bf(v1.x); a[5] = (short)f2bf(v1.y);
                a[6] = (short)f2bf(v1.z); a[7] = (short)f2bf(v1.w);
                aX[kt][f] = a;
            }
    }
    {
        const float* s0 = S + (size_t)r0 * DD;
        const float* s1 = S + (size_t)r1 * DD;
#pragma unroll
        for (int kt = 0; kt < 4; ++kt)
#pragma unroll
            for (int f = 0; f < 2; ++f) {
                const float* p = (f ? s1 : s0) + kt * 32 + lg * 8;
                float4 v0 = *(const float4*)(p);
                float4 v1 = *(const float4*)(p + 4);
                bf16x8 a;
                a[0] = (short)f2bf(v0.x); a[1] = (short)f2bf(v0.y);
                a[2] = (short)f2bf(v0.z); a[3] = (short)f2bf(v0.w);
                a[4] = (short)f2bf(v1.x); a[5] = (short)f2bf(v1.y);
                a[6] = (short)f2bf(v1.z); a[7] = (short)f2bf(v1.w);
                aS[kt][f] = a;
            }
    }
    if (t < 64) {
        int gr = node0 + t;
        degs[t] = (gr < NNODES) ? degf[gr] : 0.f;
    }

    // ---- weight-half staging (triple-buffered 16KB halves) ----
    auto issue_half = [&](int h) {
        const unsigned short* src = wfrag + (size_t)h * 8192 + (w * 4) * 512 + l * 8;
        unsigned short* dst = H + (h % 3) * 8192 + (w * 4) * 512;
#pragma unroll
        for (int i = 0; i < 4; ++i)
            gload_lds16(src + i * 512, dst + i * 512, l);
    };
    issue_half(0);
    issue_half(1);

    f32x4 zz = { 0.f, 0.f, 0.f, 0.f };
    f32x4 acc1[2][4], acc2[2][4], acc3[2][4], accO[2][4];
#pragma unroll
    for (int f = 0; f < 2; ++f)
#pragma unroll
        for (int c = 0; c < 4; ++c) {
            acc1[f][c] = zz; acc2[f][c] = zz; acc3[f][c] = zz; accO[f][c] = zz;
        }

    float dgA0 = 0.f, dgA1 = 0.f;

    auto bload = [&](const unsigned short* Hb, int ktl, int c) -> bf16x8 {
        return *(const bf16x8*)(Hb + (((ktl * 8) + wc * 4 + c) << 9) + l * 8);
    };
    auto p0h = [&](auto HC) {                       // Wn: X->acc1, S->acc2
        constexpr int h = decltype(HC)::value;
        const unsigned short* Hb = H + (h % 3) * 8192;
#pragma unroll
        for (int ktl = 0; ktl < 2; ++ktl) {
            const int kt = (h & 1) * 2 + ktl;
#pragma unroll
            for (int c = 0; c < 4; ++c) {
                bf16x8 b = bload(Hb, ktl, c);
                acc1[0][c] = MFMA(aX[kt][0], b, acc1[0][c]);
                acc1[1][c] = MFMA(aX[kt][1], b, acc1[1][c]);
                acc2[0][c] = MFMA(aS[kt][0], b, acc2[0][c]);
                acc2[1][c] = MFMA(aS[kt][1], b, acc2[1][c]);
            }
        }
    };
    auto we1h = [&](auto HC) {                      // We1: deg*X -> acc3
        constexpr int h = decltype(HC)::value;
        const unsigned short* Hb = H + (h % 3) * 8192;
#pragma unroll
        for (int ktl = 0; ktl < 2; ++ktl) {
            const int kt = (h & 1) * 2 + ktl;
            bf16x8 a0, a1;
#pragma unroll
            for (int j = 0; j < 8; ++j) {
                a0[j] = (short)f2bf(bf2f((unsigned short)aX[kt][0][j]) * dgA0);
                a1[j] = (short)f2bf(bf2f((unsigned short)aX[kt][1][j]) * dgA1);
            }
#pragma unroll
            for (int c = 0; c < 4; ++c) {
                bf16x8 b = bload(Hb, ktl, c);
                acc3[0][c] = MFMA(a0, b, acc3[0][c]);
                acc3[1][c] = MFMA(a1, b, acc3[1][c]);
            }
        }
    };
    auto we2h = [&](auto HC) {                      // We2: S -> acc3
        constexpr int h = decltype(HC)::value;
        const unsigned short* Hb = H + (h % 3) * 8192;
#pragma unroll
        for (int ktl = 0; ktl < 2; ++ktl) {
            const int kt = (h & 1) * 2 + ktl;
#pragma unroll
            for (int c = 0; c < 4; ++c) {
                bf16x8 b = bload(Hb, ktl, c);
                acc3[0][c] = MFMA(aS[kt][0], b, acc3[0][c]);
                acc3[1][c] = MFMA(aS[kt][1], b, acc3[1][c]);
            }
        }
    };
    auto wuh = [&](auto HC) {                       // Wu*: G -> accO
        constexpr int h = decltype(HC)::value;
        const unsigned short* Hb = H + (h % 3) * 8192;
#pragma unroll
        for (int ktl = 0; ktl < 2; ++ktl) {
            const int kt = (h & 1) * 2 + ktl;
            bf16x8 g0 = *(const bf16x8*)(Gs + (rb + l16) * 136 + kt * 32 + lg * 8);
            bf16x8 g1 = *(const bf16x8*)(Gs + (rb + 16 + l16) * 136 + kt * 32 + lg * 8);
#pragma unroll
            for (int c = 0; c < 4; ++c) {
                bf16x8 b = bload(Hb, ktl, c);
                accO[0][c] = MFMA(g0, b, accO[0][c]);
                accO[1][c] = MFMA(g1, b, accO[1][c]);
            }
        }
    };
    auto epi = [&](f32x4 (&acc)[2][4], const float* __restrict__ bias, bool useDeg) {
#pragma unroll
        for (int f = 0; f < 2; ++f)
#pragma unroll
            for (int c = 0; c < 4; ++c) {
                int col = (wc * 4 + c) * 16 + l16;
                float bc = bias[col];
#pragma unroll
                for (int r = 0; r < 4; ++r) {
                    int row = rb + f * 16 + lg * 4 + r;
                    float v = acc[f][c][r] + (useDeg ? degs[row] * bc : bc);
                    Gs[row * 136 + col] = f2bf(gelu_exact(v));
                }
            }
    };

    // ---- 6 phases x 2 halves, counted-vmcnt pipeline ----
    HALF_PRE(0);
    dgA0 = degs[rb + l16];
    dgA1 = degs[rb + 16 + l16];
    p0h(Int<0>{});
    HALF_PRE(1);  p0h(Int<1>{});

    HALF_PRE(2);  epi(acc1, bn, false);  BARX();  wuh(Int<2>{});   // Wu0
    HALF_PRE(3);  wuh(Int<3>{});

    HALF_PRE(4);  we1h(Int<4>{});
    HALF_PRE(5);  we1h(Int<5>{});

    HALF_PRE(6);  we2h(Int<6>{});
    HALF_PRE(7);  we2h(Int<7>{});

    HALF_PRE(8);  epi(acc2, bn, true);   BARX();  wuh(Int<8>{});   // Wu1
    HALF_PRE(9);  wuh(Int<9>{});

    HALF_PRE(10); epi(acc3, be, true);   BARX();  wuh(Int<10>{});  // Wu2
    HALF_PRE(11); wuh(Int<11>{});

    // ---- store ----
#pragma unroll
    for (int f = 0; f < 2; ++f)
#pragma unroll
        for (int c = 0; c < 4; ++c) {
            int col = (wc * 4 + c) * 16 + l16;
            float bc = bu[col];
#pragma unroll
            for (int r = 0; r < 4; ++r) {
                int grow = node0 + rb + f * 16 + lg * 4 + r;
                if (grow < NNODES)
                    out[(size_t)grow * DD + col] = accO[f][c][r] + bc;
            }
        }
}

extern "C" void kernel_launch(void* const* d_in, const int* in_sizes, int n_in,
                              void* d_out, int out_size, void* d_ws, size_t ws_size,
                              hipStream_t stream) {
    const float* x  = (const float*)d_in[0];
    const int*   ei = (const int*)d_in[1];
    const float* Wn = (const float*)d_in[2];
    const float* bn = (const float*)d_in[3];
    const float* We = (const float*)d_in[4];
    const float* be = (const float*)d_in[5];
    const float* Wu = (const float*)d_in[6];
    const float* bu = (const float*)d_in[7];

    float* out = (float*)d_out;
    float* S   = out;   // S lives in d_out; fused2 reads own rows before storing

    // ws layout: wfrag | degf | cnt | off | bsum | edst | [xbf]
    unsigned short* wfrag = (unsigned short*)d_ws;
    float* degf = (float*)((char*)d_ws + 196608);
    int* cnt  = (int*)((char*)d_ws + 596608);
    int* off  = (int*)((char*)d_ws + 996608);
    int* bsum = (int*)((char*)d_ws + 1396608);
    int* edst = (int*)((char*)d_ws + 1398656);
    unsigned short* xbf = (unsigned short*)((char*)d_ws + 3798656);
    const size_t need_xbf = 3798656 + (size_t)NNODES * DD * 2;   // ~29.4 MB
    const bool use_xbf = (ws_size >= need_xbf);

    size_t lds_bytes = 3 * 8192 * 2 + 64 * 136 * 2 + 64 * 4;     // 66816
    int fblocks = (NNODES + 63) / 64;                            // 1563
    int nb = (NNODES + SCAN_B - 1) / SCAN_B;                     // 196

    cvtw2_k<<<48, 256, 0, stream>>>(Wn, We, Wu, wfrag);
    if (use_xbf)
        cvtx_k<<<(NNODES * DD / 8 + 255) / 256, 256, 0, stream>>>(x, xbf);
    hipMemsetAsync(cnt, 0, (size_t)NNODES * sizeof(int), stream);
    hist_k<<<(NEDGES + 255) / 256, 256, 0, stream>>>(ei, cnt);
    scan_local<<<nb, SCAN_B, 0, stream>>>(cnt, off, bsum);
    scan_bsum<<<1, SCAN_B, 0, stream>>>(bsum, nb);
    scan_add<<<(NNODES + 255) / 256, 256, 0, stream>>>(off, bsum, cnt, degf);
    fill_k<<<(NEDGES + 255) / 256, 256, 0, stream>>>(ei, off, edst);

    if (use_xbf) {
        agg_bf_k<<<NNODES / 4, 256, 0, stream>>>(off, edst, xbf, S);
        fused2_k<true><<<fblocks, 256, lds_bytes, stream>>>(x, xbf, S, degf, wfrag,
                                                            bn, be, bu, out);
    } else {
        agg_k<<<NNODES / 4, 256, 0, stream>>>(off, edst, x, S);
        fused2_k<false><<<fblocks, 256, lds_bytes, stream>>>(x, nullptr, S, degf, wfrag,
                                                             bn, be, bu, out);
    }
}

// Round 4
// 210.589 us; speedup vs baseline: 6.4222x; 1.1348x over previous
//
#include <hip/hip_runtime.h>
#include <hip/hip_bf16.h>
#include <math.h>

#define NNODES 100000
#define NEDGES 600000
#define DD 128
#define SCAN_B 512

typedef __attribute__((ext_vector_type(8))) short bf16x8;
typedef __attribute__((ext_vector_type(4))) float f32x4;

static __device__ __forceinline__ unsigned short f2bf(float f) {
    __hip_bfloat16 h = __float2bfloat16(f);   // HW RNE cvt on gfx950
    return __builtin_bit_cast(unsigned short, h);
}
static __device__ __forceinline__ float bf2f(unsigned short h) {
    unsigned u = ((unsigned)h) << 16;
    return __builtin_bit_cast(float, u);
}
// tanh-approx GELU as sigmoid: v * sigmoid(1.595769*v + 0.071355*v^3), exp2-folded.
// |err| vs exact-erf gelu <= ~3e-3 absolute; harness threshold is 1.07.
static __device__ __forceinline__ float gelu_fast(float v) {
    float w = v * (-2.302203846f - 0.102943150f * v * v);
    return v / (1.0f + exp2f(w));
}

#if __has_builtin(__builtin_amdgcn_global_load_lds)
#define HAVE_GLDS 1
#else
#define HAVE_GLDS 0
#endif

static __device__ __forceinline__ void gload_lds16(const unsigned short* g, unsigned short* s, int lane) {
#if HAVE_GLDS
    (void)lane;
    __builtin_amdgcn_global_load_lds((const __attribute__((address_space(1))) void*)g,
                                     (__attribute__((address_space(3))) void*)s, 16, 0, 0);
#else
    *(bf16x8*)(s + lane * 8) = *(const bf16x8*)g;
#endif
}

#define MFMA(a, b, c) __builtin_amdgcn_mfma_f32_16x16x32_bf16(a, b, c, 0, 0, 0)
#define BARX() do { asm volatile("s_waitcnt lgkmcnt(0)" ::: "memory"); \
                    __builtin_amdgcn_s_barrier(); } while (0)
// 24-quarter pipeline, 2-deep prefetch, 3 buffers. At PRE(q): outstanding =
// quarter q (2 loads) + q+1 (2 loads); vmcnt(2) completes q. Issue q+2 after
// the barrier: it targets buf (q+2)%3 = (q-1)%3, whose readers (body q-1)
// all drained their ds_reads via lgkmcnt(0) before this barrier.
#define PREQ(q) do { \
    if ((q) == 23) asm volatile("s_waitcnt vmcnt(0)" ::: "memory"); \
    else           asm volatile("s_waitcnt vmcnt(2)" ::: "memory"); \
    asm volatile("s_waitcnt lgkmcnt(0)" ::: "memory"); \
    __builtin_amdgcn_s_barrier(); \
    if ((q) + 2 < 24) issue_q((q) + 2); } while (0)

// ---------- prep: weights->frag-major bf16 | zero cnt | x->bf16 ----------
__global__ __launch_bounds__(256) void prep_k(const float* __restrict__ x,
                                              const float* __restrict__ Wn,
                                              const float* __restrict__ We,
                                              const float* __restrict__ Wu,
                                              unsigned short* __restrict__ wfrag,
                                              int* __restrict__ cnt,
                                              unsigned short* __restrict__ xb) {
    int b = blockIdx.x;
    int t = threadIdx.x;
    if (b < 48) {
        // wfrag layout: [tile][kt][ct][lane][8], tiles = [Wn,Wu0,We1,We2,Wu1,Wu2]
        int tid = b * 256 + t;
        int l = tid & 63;
        int ct = (tid >> 6) & 7;
        int kt = (tid >> 9) & 3;
        int tile = tid >> 11;
        int n = ct * 16 + (l & 15);
        int k = kt * 32 + (l >> 4) * 8;
        const float* src;
        switch (tile) {
            case 0:  src = Wn + (size_t)n * 128 + k;        break;
            case 1:  src = Wu + (size_t)n * 384 + k;        break;
            case 2:  src = We + (size_t)n * 256 + k;        break;
            case 3:  src = We + (size_t)n * 256 + 128 + k;  break;
            case 4:  src = Wu + (size_t)n * 384 + 128 + k;  break;
            default: src = Wu + (size_t)n * 384 + 256 + k;  break;
        }
        unsigned short o[8];
#pragma unroll
        for (int j = 0; j < 8; ++j) o[j] = f2bf(src[j]);
        *(bf16x8*)(wfrag + (size_t)tid * 8) = *(bf16x8*)o;
    } else if (b < 48 + 391) {
        int i = (b - 48) * 256 + t;
        if (i < NNODES) cnt[i] = 0;
    } else {
        int i = (b - 439) * 256 + t;   // < 1,600,000 exactly
        float4 v0 = *(const float4*)(x + (size_t)i * 8);
        float4 v1 = *(const float4*)(x + (size_t)i * 8 + 4);
        unsigned short o[8] = { f2bf(v0.x), f2bf(v0.y), f2bf(v0.z), f2bf(v0.w),
                                f2bf(v1.x), f2bf(v1.y), f2bf(v1.z), f2bf(v1.w) };
        *(bf16x8*)(xb + (size_t)i * 8) = *(bf16x8*)o;
    }
}

// ---------------- CSR build ----------------
__global__ __launch_bounds__(256) void hist_k(const int* __restrict__ ei, int* __restrict__ cnt) {
    int e = blockIdx.x * 256 + threadIdx.x;
    if (e < NEDGES) atomicAdd(&cnt[ei[e]], 1);
}

__global__ __launch_bounds__(SCAN_B) void scan_local(const int* __restrict__ cnt,
                                                     int* __restrict__ off,
                                                     int* __restrict__ bsum) {
    __shared__ int sh[SCAN_B];
    int i = blockIdx.x * SCAN_B + threadIdx.x;
    int v = (i < NNODES) ? cnt[i] : 0;
    sh[threadIdx.x] = v;
    __syncthreads();
    for (int d = 1; d < SCAN_B; d <<= 1) {
        int t = (threadIdx.x >= d) ? sh[threadIdx.x - d] : 0;
        __syncthreads();
        sh[threadIdx.x] += t;
        __syncthreads();
    }
    if (i < NNODES) off[i] = sh[threadIdx.x] - v;
    if (threadIdx.x == SCAN_B - 1) bsum[blockIdx.x] = sh[threadIdx.x];
}

__global__ __launch_bounds__(SCAN_B) void scan_bsum(int* __restrict__ bsum, int nb) {
    __shared__ int sh[SCAN_B];
    int v = (threadIdx.x < nb) ? bsum[threadIdx.x] : 0;
    sh[threadIdx.x] = v;
    __syncthreads();
    for (int d = 1; d < SCAN_B; d <<= 1) {
        int t = (threadIdx.x >= d) ? sh[threadIdx.x - d] : 0;
        __syncthreads();
        sh[threadIdx.x] += t;
        __syncthreads();
    }
    if (threadIdx.x < nb) bsum[threadIdx.x] = sh[threadIdx.x] - v;
}

__global__ __launch_bounds__(256) void scan_add(int* __restrict__ off,
                                                const int* __restrict__ bsum,
                                                const int* __restrict__ cnt,
                                                float* __restrict__ degf) {
    int i = blockIdx.x * 256 + threadIdx.x;
    if (i < NNODES) {
        off[i] += bsum[i / SCAN_B];
        degf[i] = (float)cnt[i];
    }
}

__global__ __launch_bounds__(256) void fill_k(const int* __restrict__ ei,
                                              int* __restrict__ off,
                                              int* __restrict__ edst) {
    int e = blockIdx.x * 256 + threadIdx.x;
    if (e >= NEDGES) return;
    int s = ei[e], d = ei[NEDGES + e];
    int pos = atomicAdd(&off[s], 1);
    edst[pos] = d;
}

// ---------------- aggregate S[v] = sum x[dst] ----------------
// OUT_BF: write bf16 rows to Sb; else f32 rows to Sf.
template <bool IN_BF, bool OUT_BF>
__global__ __launch_bounds__(256) void agg_k(const int* __restrict__ off,
                                             const int* __restrict__ edst,
                                             const float* __restrict__ xf,
                                             const unsigned short* __restrict__ xb,
                                             float* Sf, unsigned short* Sb) {
    int node = (blockIdx.x * 256 + threadIdx.x) >> 6;
    if (node >= NNODES) return;
    int lane = threadIdx.x & 63;
    int end = off[node];
    int beg = node ? off[node - 1] : 0;
    float a0 = 0.f, a1 = 0.f, b0 = 0.f, b1 = 0.f;
    int e = beg;
    for (; e + 1 < end; e += 2) {
        if constexpr (IN_BF) {
            unsigned v0 = *(const unsigned*)(xb + (size_t)edst[e] * DD + lane * 2);
            unsigned v1 = *(const unsigned*)(xb + (size_t)edst[e + 1] * DD + lane * 2);
            a0 += bf2f((unsigned short)(v0 & 0xffff)); a1 += bf2f((unsigned short)(v0 >> 16));
            b0 += bf2f((unsigned short)(v1 & 0xffff)); b1 += bf2f((unsigned short)(v1 >> 16));
        } else {
            float2 v0 = *(const float2*)(xf + (size_t)edst[e] * DD + lane * 2);
            float2 v1 = *(const float2*)(xf + (size_t)edst[e + 1] * DD + lane * 2);
            a0 += v0.x; a1 += v0.y; b0 += v1.x; b1 += v1.y;
        }
    }
    if (e < end) {
        if constexpr (IN_BF) {
            unsigned v0 = *(const unsigned*)(xb + (size_t)edst[e] * DD + lane * 2);
            a0 += bf2f((unsigned short)(v0 & 0xffff)); a1 += bf2f((unsigned short)(v0 >> 16));
        } else {
            float2 v0 = *(const float2*)(xf + (size_t)edst[e] * DD + lane * 2);
            a0 += v0.x; a1 += v0.y;
        }
    }
    float r0 = a0 + b0, r1 = a1 + b1;
    if constexpr (OUT_BF) {
        unsigned p = (unsigned)f2bf(r0) | ((unsigned)f2bf(r1) << 16);
        *(unsigned*)(Sb + (size_t)node * DD + lane * 2) = p;
    } else {
        float2 r = { r0, r1 };
        *(float2*)(Sf + (size_t)node * DD + lane * 2) = r;
    }
}

// ---------------- fused GEMMs, 24-quarter pipeline ----------------
// out[v] = gelu(x@Wn.T+bn)@Wu0.T + gelu(S@Wn.T+deg*bn)@Wu1.T
//        + gelu(deg*(x@We1.T+be)+S@We2.T)@Wu2.T + bu
// MODE 0: x f32, S f32 (aliases out). MODE 1: x bf16, S f32 (aliases out).
// MODE 2: x bf16, S bf16 in ws (no aliasing).
template <int MODE>
__global__ __launch_bounds__(256, 2) void fused3_k(const float* __restrict__ xf,
                                                   const unsigned short* __restrict__ xb,
                                                   const float* Sf,
                                                   const unsigned short* __restrict__ Sb,
                                                   const float* __restrict__ degf,
                                                   const unsigned short* __restrict__ wfrag,
                                                   const float* __restrict__ bn,
                                                   const float* __restrict__ be,
                                                   const float* __restrict__ bu,
                                                   float* out) {
    __shared__ unsigned short Q[3][4096];     // 3 x 8KB quarter-tile buffers
    __shared__ unsigned short Gs[64 * 136];   // gelu output, transposed access
    __shared__ float degs[64];

    const int t = threadIdx.x;
    const int w = t >> 6;
    const int l = t & 63;
    const int wc = w & 1;            // col half: ct in [wc*4, wc*4+4)
    const int rb = (w >> 1) * 32;    // row base within the 64-row tile
    const int l16 = l & 15;
    const int lg = l >> 4;
    const int node0 = blockIdx.x * 64;

    int r0 = node0 + rb + l16;      if (r0 > NNODES - 1) r0 = NNODES - 1;
    int r1 = node0 + rb + 16 + l16; if (r1 > NNODES - 1) r1 = NNODES - 1;

    auto loadA_bf = [&](const unsigned short* rowp, bf16x8 (&A)[4][2], int f) {
#pragma unroll
        for (int kt = 0; kt < 4; ++kt)
            A[kt][f] = *(const bf16x8*)(rowp + kt * 32 + lg * 8);
    };
    auto loadA_f32 = [&](const float* rowp, bf16x8 (&A)[4][2], int f) {
#pragma unroll
        for (int kt = 0; kt < 4; ++kt) {
            const float* p = rowp + kt * 32 + lg * 8;
            float4 v0 = *(const float4*)(p);
            float4 v1 = *(const float4*)(p + 4);
            bf16x8 a;
            a[0] = (short)f2bf(v0.x); a[1] = (short)f2bf(v0.y);
            a[2] = (short)f2bf(v0.z); a[3] = (short)f2bf(v0.w);
            a[4] = (short)f2bf(v1.x); a[5] = (short)f2bf(v1.y);
            a[6] = (short)f2bf(v1.z); a[7] = (short)f2bf(v1.w);
            A[kt][f] = a;
        }
    };

    bf16x8 aX[4][2], aS[4][2];
    if constexpr (MODE >= 1) {
        loadA_bf(xb + (size_t)r0 * DD, aX, 0);
        loadA_bf(xb + (size_t)r1 * DD, aX, 1);
    } else {
        loadA_f32(xf + (size_t)r0 * DD, aX, 0);
        loadA_f32(xf + (size_t)r1 * DD, aX, 1);
    }
    if constexpr (MODE == 2) {
        loadA_bf(Sb + (size_t)r0 * DD, aS, 0);
        loadA_bf(Sb + (size_t)r1 * DD, aS, 1);
    } else {
        loadA_f32(Sf + (size_t)r0 * DD, aS, 0);
        loadA_f32(Sf + (size_t)r1 * DD, aS, 1);
    }
    if (t < 64) {
        int gr = node0 + t;
        degs[t] = (gr < NNODES) ? degf[gr] : 0.f;
    }

    // quarter q source: wfrag + q*4096 u16; wave w stages its 1024-u16 segment.
    auto issue_q = [&](int q) {
        const unsigned short* src = wfrag + (size_t)q * 4096 + w * 1024 + l * 8;
        unsigned short* dst = &Q[q % 3][w * 1024];
        gload_lds16(src, dst, l);
        gload_lds16(src + 512, dst + 512, l);
    };
    issue_q(0);
    issue_q(1);

    f32x4 zz = { 0.f, 0.f, 0.f, 0.f };
    f32x4 acc1[2][4], acc2[2][4], acc3[2][4], accO[2][4];
#pragma unroll
    for (int f = 0; f < 2; ++f)
#pragma unroll
        for (int c = 0; c < 4; ++c) {
            acc1[f][c] = zz; acc2[f][c] = zz; acc3[f][c] = zz; accO[f][c] = zz;
        }

    auto bload = [&](int q3, int c) -> bf16x8 {
        return *(const bf16x8*)(&Q[q3][(wc * 4 + c) * 512 + l * 8]);
    };
    auto body_wn = [&](int kt, int q3) {      // Wn: X->acc1, S->acc2 (shared B)
        __builtin_amdgcn_s_setprio(1);
#pragma unroll
        for (int c = 0; c < 4; ++c) {
            bf16x8 b = bload(q3, c);
            acc1[0][c] = MFMA(aX[kt][0], b, acc1[0][c]);
            acc1[1][c] = MFMA(aX[kt][1], b, acc1[1][c]);
            acc2[0][c] = MFMA(aS[kt][0], b, acc2[0][c]);
            acc2[1][c] = MFMA(aS[kt][1], b, acc2[1][c]);
        }
        __builtin_amdgcn_s_setprio(0);
    };
    auto body_A = [&](int kt, int q3, bf16x8 (&A)[4][2], f32x4 (&acc)[2][4]) {
        __builtin_amdgcn_s_setprio(1);
#pragma unroll
        for (int c = 0; c < 4; ++c) {
            bf16x8 b = bload(q3, c);
            acc[0][c] = MFMA(A[kt][0], b, acc[0][c]);
            acc[1][c] = MFMA(A[kt][1], b, acc[1][c]);
        }
        __builtin_amdgcn_s_setprio(0);
    };
    auto body_wu = [&](int kt, int q3) {      // Wu*: G -> accO
        bf16x8 g0 = *(const bf16x8*)(Gs + (rb + l16) * 136 + kt * 32 + lg * 8);
        bf16x8 g1 = *(const bf16x8*)(Gs + (rb + 16 + l16) * 136 + kt * 32 + lg * 8);
        __builtin_amdgcn_s_setprio(1);
#pragma unroll
        for (int c = 0; c < 4; ++c) {
            bf16x8 b = bload(q3, c);
            accO[0][c] = MFMA(g0, b, accO[0][c]);
            accO[1][c] = MFMA(g1, b, accO[1][c]);
        }
        __builtin_amdgcn_s_setprio(0);
    };
    // degMode 0: v+bias; 1: v+deg*bias; 2: v (bias pre-folded)
    auto epi = [&](f32x4 (&acc)[2][4], const float* bias, int degMode) {
#pragma unroll
        for (int f = 0; f < 2; ++f)
#pragma unroll
            for (int c = 0; c < 4; ++c) {
                int col = (wc * 4 + c) * 16 + l16;
                float bc = (degMode == 2) ? 0.f : bias[col];
#pragma unroll
                for (int r = 0; r < 4; ++r) {
                    int row = rb + f * 16 + lg * 4 + r;
                    float v = acc[f][c][r];
                    if (degMode == 0) v += bc;
                    if (degMode == 1) v += degs[row] * bc;
                    Gs[row * 136 + col] = f2bf(gelu_fast(v));
                }
            }
    };
    auto fold3 = [&] {   // acc3 = deg[row] * (acc3 + be[col]); register-only
#pragma unroll
        for (int f = 0; f < 2; ++f)
#pragma unroll
            for (int c = 0; c < 4; ++c) {
                int col = (wc * 4 + c) * 16 + l16;
                float bec = be[col];
#pragma unroll
                for (int r = 0; r < 4; ++r) {
                    int row = rb + f * 16 + lg * 4 + r;
                    acc3[f][c][r] = degs[row] * (acc3[f][c][r] + bec);
                }
            }
    };

    // tiles: q0-3 Wn | q4-7 Wu0 | q8-11 We1 | q12-15 We2 | q16-19 Wu1 | q20-23 Wu2
    PREQ(0);  body_wn(0, 0);
    PREQ(1);  body_wn(1, 1);
    PREQ(2);  body_wn(2, 2);
    PREQ(3);  body_wn(3, 0);
    PREQ(4);  epi(acc1, bn, 0); BARX(); body_wu(0, 1);
    PREQ(5);  body_wu(1, 2);
    PREQ(6);  body_wu(2, 0);
    PREQ(7);  body_wu(3, 1);
    PREQ(8);  body_A(0, 2, aX, acc3);
    PREQ(9);  body_A(1, 0, aX, acc3);
    PREQ(10); body_A(2, 1, aX, acc3);
    PREQ(11); body_A(3, 2, aX, acc3);
    fold3();
    PREQ(12); body_A(0, 0, aS, acc3);
    PREQ(13); body_A(1, 1, aS, acc3);
    PREQ(14); body_A(2, 2, aS, acc3);
    PREQ(15); body_A(3, 0, aS, acc3);
    PREQ(16); epi(acc2, bn, 1); BARX(); body_wu(0, 1);
    PREQ(17); body_wu(1, 2);
    PREQ(18); body_wu(2, 0);
    PREQ(19); body_wu(3, 1);
    PREQ(20); epi(acc3, nullptr, 2); BARX(); body_wu(0, 2);
    PREQ(21); body_wu(1, 0);
    PREQ(22); body_wu(2, 1);
    PREQ(23); body_wu(3, 2);

    // ---- store ----
#pragma unroll
    for (int f = 0; f < 2; ++f)
#pragma unroll
        for (int c = 0; c < 4; ++c) {
            int col = (wc * 4 + c) * 16 + l16;
            float bc = bu[col];
#pragma unroll
            for (int r = 0; r < 4; ++r) {
                int grow = node0 + rb + f * 16 + lg * 4 + r;
                if (grow < NNODES)
                    out[(size_t)grow * DD + col] = accO[f][c][r] + bc;
            }
        }
}

extern "C" void kernel_launch(void* const* d_in, const int* in_sizes, int n_in,
                              void* d_out, int out_size, void* d_ws, size_t ws_size,
                              hipStream_t stream) {
    const float* x  = (const float*)d_in[0];
    const int*   ei = (const int*)d_in[1];
    const float* Wn = (const float*)d_in[2];
    const float* bn = (const float*)d_in[3];
    const float* We = (const float*)d_in[4];
    const float* be = (const float*)d_in[5];
    const float* Wu = (const float*)d_in[6];
    const float* bu = (const float*)d_in[7];

    float* out = (float*)d_out;

    // ws layout: wfrag(196608) | degf | cnt | off | bsum | edst | xbf | Sbf
    unsigned short* wfrag = (unsigned short*)d_ws;
    float* degf = (float*)((char*)d_ws + 196608);
    int* cnt  = (int*)((char*)d_ws + 596608);
    int* off  = (int*)((char*)d_ws + 996608);
    int* bsum = (int*)((char*)d_ws + 1396608);
    int* edst = (int*)((char*)d_ws + 1398656);
    unsigned short* xbf = (unsigned short*)((char*)d_ws + 3798656);
    unsigned short* Sbf = (unsigned short*)((char*)d_ws + 29398656);

    int mode = 0;
    if (ws_size >= 29398656ULL + 25600000ULL) mode = 2;
    else if (ws_size >= 3798656ULL + 25600000ULL) mode = 1;

    int fblocks = (NNODES + 63) / 64;            // 1563
    int nb = (NNODES + SCAN_B - 1) / SCAN_B;     // 196
    int pblocks = (mode >= 1) ? (439 + NNODES * DD / 8 / 256) : 439;

    prep_k<<<pblocks, 256, 0, stream>>>(x, Wn, We, Wu, wfrag, cnt, xbf);
    hist_k<<<(NEDGES + 255) / 256, 256, 0, stream>>>(ei, cnt);
    scan_local<<<nb, SCAN_B, 0, stream>>>(cnt, off, bsum);
    scan_bsum<<<1, SCAN_B, 0, stream>>>(bsum, nb);
    scan_add<<<(NNODES + 255) / 256, 256, 0, stream>>>(off, bsum, cnt, degf);
    fill_k<<<(NEDGES + 255) / 256, 256, 0, stream>>>(ei, off, edst);

    if (mode == 2) {
        agg_k<true, true><<<NNODES / 4, 256, 0, stream>>>(off, edst, x, xbf, nullptr, Sbf);
        fused3_k<2><<<fblocks, 256, 0, stream>>>(x, xbf, nullptr, Sbf, degf, wfrag,
                                                 bn, be, bu, out);
    } else if (mode == 1) {
        agg_k<true, false><<<NNODES / 4, 256, 0, stream>>>(off, edst, x, xbf, out, nullptr);
        fused3_k<1><<<fblocks, 256, 0, stream>>>(x, xbf, out, nullptr, degf, wfrag,
                                                 bn, be, bu, out);
    } else {
        agg_k<false, false><<<NNODES / 4, 256, 0, stream>>>(off, edst, x, nullptr, out, nullptr);
        fused3_k<0><<<fblocks, 256, 0, stream>>>(x, nullptr, out, nullptr, degf, wfrag,
                                                 bn, be, bu, out);
    }
}

// Round 5
// 200.425 us; speedup vs baseline: 6.7479x; 1.0507x over previous
//
#include <hip/hip_runtime.h>
#include <hip/hip_bf16.h>
#include <math.h>

#define NNODES 100000
#define NEDGES 600000
#define DD 128
#define SCAN_B 512

typedef __attribute__((ext_vector_type(8))) short bf16x8;
typedef __attribute__((ext_vector_type(4))) float f32x4;

static __device__ __forceinline__ unsigned short f2bf(float f) {
    __hip_bfloat16 h = __float2bfloat16(f);   // HW RNE cvt
    return __builtin_bit_cast(unsigned short, h);
}
static __device__ __forceinline__ float bf2f(unsigned short h) {
    unsigned u = ((unsigned)h) << 16;
    return __builtin_bit_cast(float, u);
}
// tanh-approx GELU via sigmoid, exp2-folded. |err| <= ~3e-3 (threshold 1.07).
static __device__ __forceinline__ float gelu_fast(float v) {
    float w = v * (-2.302203846f - 0.102943150f * v * v);
    return v / (1.0f + exp2f(w));
}

#if __has_builtin(__builtin_amdgcn_global_load_lds)
#define HAVE_GLDS 1
#else
#define HAVE_GLDS 0
#endif

static __device__ __forceinline__ void gload_lds16(const unsigned short* g, unsigned short* s, int lane) {
#if HAVE_GLDS
    (void)lane;
    __builtin_amdgcn_global_load_lds((const __attribute__((address_space(1))) void*)g,
                                     (__attribute__((address_space(3))) void*)s, 16, 0, 0);
#else
    *(bf16x8*)(s + lane * 8) = *(const bf16x8*)g;
#endif
}

#define MFMA(a, b, c) __builtin_amdgcn_mfma_f32_16x16x32_bf16(a, b, c, 0, 0, 0)
#define BARX() do { asm volatile("s_waitcnt lgkmcnt(0)" ::: "memory"); \
                    __builtin_amdgcn_s_barrier(); } while (0)
// 24 quarters, 5 buffers, depth-4 prefetch, ONE global_load_lds per wave per
// quarter. At PREQ(q): outstanding quarters q..min(q+3,23); wait so quarter q
// is complete -> vmcnt(min(q+3,23)-q). Issue q+4 post-barrier: it targets
// buf (q+4)%5 == (q-1)%5, whose readers (body q-1) drained their ds_reads
// via lgkmcnt(0) before this barrier.
#define PREQ(q) do { \
    if ((q) <= 20)      asm volatile("s_waitcnt vmcnt(3)" ::: "memory"); \
    else if ((q) == 21) asm volatile("s_waitcnt vmcnt(2)" ::: "memory"); \
    else if ((q) == 22) asm volatile("s_waitcnt vmcnt(1)" ::: "memory"); \
    else                asm volatile("s_waitcnt vmcnt(0)" ::: "memory"); \
    asm volatile("s_waitcnt lgkmcnt(0)" ::: "memory"); \
    __builtin_amdgcn_s_barrier(); \
    if ((q) + 4 < 24) issue_q((q) + 4); } while (0)

// ---------- prep: weights->frag-major bf16 | zero cnt | x->bf16 ----------
__global__ __launch_bounds__(256) void prep_k(const float* __restrict__ x,
                                              const float* __restrict__ Wn,
                                              const float* __restrict__ We,
                                              const float* __restrict__ Wu,
                                              unsigned short* __restrict__ wfrag,
                                              int* __restrict__ cnt,
                                              unsigned short* __restrict__ xb) {
    int b = blockIdx.x;
    int t = threadIdx.x;
    if (b < 48) {
        // wfrag layout: [tile][kt][ct][lane][8], tiles = [Wn,Wu0,We1,We2,Wu1,Wu2]
        int tid = b * 256 + t;
        int l = tid & 63;
        int ct = (tid >> 6) & 7;
        int kt = (tid >> 9) & 3;
        int tile = tid >> 11;
        int n = ct * 16 + (l & 15);
        int k = kt * 32 + (l >> 4) * 8;
        const float* src;
        switch (tile) {
            case 0:  src = Wn + (size_t)n * 128 + k;        break;
            case 1:  src = Wu + (size_t)n * 384 + k;        break;
            case 2:  src = We + (size_t)n * 256 + k;        break;
            case 3:  src = We + (size_t)n * 256 + 128 + k;  break;
            case 4:  src = Wu + (size_t)n * 384 + 128 + k;  break;
            default: src = Wu + (size_t)n * 384 + 256 + k;  break;
        }
        unsigned short o[8];
#pragma unroll
        for (int j = 0; j < 8; ++j) o[j] = f2bf(src[j]);
        *(bf16x8*)(wfrag + (size_t)tid * 8) = *(bf16x8*)o;
    } else if (b < 48 + 391) {
        int i = (b - 48) * 256 + t;
        if (i < NNODES) cnt[i] = 0;
    } else {
        int i = (b - 439) * 256 + t;   // < 1,600,000 exactly
        float4 v0 = *(const float4*)(x + (size_t)i * 8);
        float4 v1 = *(const float4*)(x + (size_t)i * 8 + 4);
        unsigned short o[8] = { f2bf(v0.x), f2bf(v0.y), f2bf(v0.z), f2bf(v0.w),
                                f2bf(v1.x), f2bf(v1.y), f2bf(v1.z), f2bf(v1.w) };
        *(bf16x8*)(xb + (size_t)i * 8) = *(bf16x8*)o;
    }
}

// ---------------- CSR build ----------------
__global__ __launch_bounds__(256) void hist_k(const int* __restrict__ ei, int* __restrict__ cnt) {
    int e = blockIdx.x * 256 + threadIdx.x;
    if (e < NEDGES) atomicAdd(&cnt[ei[e]], 1);
}

__global__ __launch_bounds__(SCAN_B) void scan_local(const int* __restrict__ cnt,
                                                     int* __restrict__ off,
                                                     int* __restrict__ bsum) {
    __shared__ int sh[SCAN_B];
    int i = blockIdx.x * SCAN_B + threadIdx.x;
    int v = (i < NNODES) ? cnt[i] : 0;
    sh[threadIdx.x] = v;
    __syncthreads();
    for (int d = 1; d < SCAN_B; d <<= 1) {
        int t = (threadIdx.x >= d) ? sh[threadIdx.x - d] : 0;
        __syncthreads();
        sh[threadIdx.x] += t;
        __syncthreads();
    }
    if (i < NNODES) off[i] = sh[threadIdx.x] - v;   // exclusive within block
    if (threadIdx.x == SCAN_B - 1) bsum[blockIdx.x] = sh[threadIdx.x];
}

// scan_add with inline bsum prefix (bsum holds RAW per-block sums).
__global__ __launch_bounds__(256) void scan_add2(int* __restrict__ off,
                                                 const int* __restrict__ bsum,
                                                 const int* __restrict__ cnt,
                                                 float* __restrict__ degf) {
    __shared__ int sp;
    int K = blockIdx.x >> 1;           // # of preceding SCAN_B-blocks
    int t = threadIdx.x;
    if (t < 64) {
        int s = 0;
        for (int j = t; j < K; j += 64) s += bsum[j];
#pragma unroll
        for (int d = 32; d; d >>= 1) s += __shfl_down(s, d, 64);
        if (t == 0) sp = s;
    }
    __syncthreads();
    int i = blockIdx.x * 256 + t;
    if (i < NNODES) {
        off[i] += sp;
        degf[i] = (float)cnt[i];
    }
}

__global__ __launch_bounds__(256) void fill_k(const int* __restrict__ ei,
                                              int* __restrict__ off,
                                              int* __restrict__ edst) {
    int e = blockIdx.x * 256 + threadIdx.x;
    if (e >= NEDGES) return;
    int s = ei[e], d = ei[NEDGES + e];
    int pos = atomicAdd(&off[s], 1);
    edst[pos] = d;
}

// ---------------- aggregate S[v] = sum x[dst] ----------------
// 1 node per wave; 4 edge-slots x 16 col-lanes; dwordx4 per edge per lane.
template <bool IN_BF, bool OUT_BF>
__global__ __launch_bounds__(256) void agg2_k(const int* __restrict__ off,
                                              const int* __restrict__ edst,
                                              const float* __restrict__ xf,
                                              const unsigned short* __restrict__ xb,
                                              float* Sf, unsigned short* Sb) {
    int node = (blockIdx.x * 256 + threadIdx.x) >> 6;
    if (node >= NNODES) return;
    int l = threadIdx.x & 63;
    int es = l >> 4;      // edge slot 0..3
    int cg = l & 15;      // col group: 8 elems
    int end = off[node];
    int beg = node ? off[node - 1] : 0;
    float acc[8] = {0.f, 0.f, 0.f, 0.f, 0.f, 0.f, 0.f, 0.f};
    for (int e = beg + es; e < end; e += 4) {
        int d = edst[e];
        if constexpr (IN_BF) {
            bf16x8 v = *(const bf16x8*)(xb + (size_t)d * DD + cg * 8);
#pragma unroll
            for (int j = 0; j < 8; ++j) acc[j] += bf2f((unsigned short)v[j]);
        } else {
            const float* p = xf + (size_t)d * DD + cg * 8;
            float4 v0 = *(const float4*)(p);
            float4 v1 = *(const float4*)(p + 4);
            acc[0] += v0.x; acc[1] += v0.y; acc[2] += v0.z; acc[3] += v0.w;
            acc[4] += v1.x; acc[5] += v1.y; acc[6] += v1.z; acc[7] += v1.w;
        }
    }
#pragma unroll
    for (int j = 0; j < 8; ++j) {
        acc[j] += __shfl_xor(acc[j], 16, 64);
        acc[j] += __shfl_xor(acc[j], 32, 64);
    }
    if (es == 0) {
        if constexpr (OUT_BF) {
            unsigned short o[8];
#pragma unroll
            for (int j = 0; j < 8; ++j) o[j] = f2bf(acc[j]);
            *(bf16x8*)(Sb + (size_t)node * DD + cg * 8) = *(bf16x8*)o;
        } else {
            float4 r0 = { acc[0], acc[1], acc[2], acc[3] };
            float4 r1 = { acc[4], acc[5], acc[6], acc[7] };
            *(float4*)(Sf + (size_t)node * DD + cg * 8) = r0;
            *(float4*)(Sf + (size_t)node * DD + cg * 8 + 4) = r1;
        }
    }
}

// ---------------- fused GEMMs: 128-row blocks, depth-4 pipeline ----------------
// out[v] = gelu(x@Wn.T+bn)@Wu0.T + gelu(S@Wn.T+deg*bn)@Wu1.T
//        + gelu(deg*(x@We1.T+be)+S@We2.T)@Wu2.T + bu
// MODE 0: x f32, S f32 (aliases out). MODE 1: x bf16, S f32 (aliases out).
// MODE 2: x bf16, S bf16 in ws. Each block reads only its own 128 S-rows.
template <int MODE>
__global__ __launch_bounds__(512) void fused4_k(const float* __restrict__ xf,
                                                const unsigned short* __restrict__ xb,
                                                const float* Sf,
                                                const unsigned short* __restrict__ Sb,
                                                const float* __restrict__ degf,
                                                const unsigned short* __restrict__ wfrag,
                                                const float* __restrict__ bn,
                                                const float* __restrict__ be,
                                                const float* __restrict__ bu,
                                                float* out) {
    extern __shared__ char smem[];
    unsigned short* Q  = (unsigned short*)smem;   // 5 x 4096 u16 (8KB quarters)
    unsigned short* Gs = Q + 5 * 4096;            // [128][136] u16
    float* degs = (float*)(Gs + 128 * 136);       // [128]

    const int t = threadIdx.x;
    const int w = t >> 6;
    const int l = t & 63;
    const int wc = w & 1;            // col half: ct in [wc*4, wc*4+4)
    const int rb = (w >> 1) * 32;    // row base within 128-row tile
    const int l16 = l & 15;
    const int lg = l >> 4;
    const int node0 = blockIdx.x * 128;

    int r0 = node0 + rb + l16;      if (r0 > NNODES - 1) r0 = NNODES - 1;
    int r1 = node0 + rb + 16 + l16; if (r1 > NNODES - 1) r1 = NNODES - 1;

    auto loadA_bf = [&](const unsigned short* rowp, bf16x8 (&A)[4][2], int f) {
#pragma unroll
        for (int kt = 0; kt < 4; ++kt)
            A[kt][f] = *(const bf16x8*)(rowp + kt * 32 + lg * 8);
    };
    auto loadA_f32 = [&](const float* rowp, bf16x8 (&A)[4][2], int f) {
#pragma unroll
        for (int kt = 0; kt < 4; ++kt) {
            const float* p = rowp + kt * 32 + lg * 8;
            float4 v0 = *(const float4*)(p);
            float4 v1 = *(const float4*)(p + 4);
            bf16x8 a;
            a[0] = (short)f2bf(v0.x); a[1] = (short)f2bf(v0.y);
            a[2] = (short)f2bf(v0.z); a[3] = (short)f2bf(v0.w);
            a[4] = (short)f2bf(v1.x); a[5] = (short)f2bf(v1.y);
            a[6] = (short)f2bf(v1.z); a[7] = (short)f2bf(v1.w);
            A[kt][f] = a;
        }
    };

    bf16x8 aX[4][2], aS[4][2];
    if constexpr (MODE >= 1) {
        loadA_bf(xb + (size_t)r0 * DD, aX, 0);
        loadA_bf(xb + (size_t)r1 * DD, aX, 1);
    } else {
        loadA_f32(xf + (size_t)r0 * DD, aX, 0);
        loadA_f32(xf + (size_t)r1 * DD, aX, 1);
    }
    if constexpr (MODE == 2) {
        loadA_bf(Sb + (size_t)r0 * DD, aS, 0);
        loadA_bf(Sb + (size_t)r1 * DD, aS, 1);
    } else {
        loadA_f32(Sf + (size_t)r0 * DD, aS, 0);
        loadA_f32(Sf + (size_t)r1 * DD, aS, 1);
    }
    // biases into registers (no mid-pipeline global loads)
    float bnc[4], bec[4], buc[4];
#pragma unroll
    for (int c = 0; c < 4; ++c) {
        int col = (wc * 4 + c) * 16 + l16;
        bnc[c] = bn[col]; bec[c] = be[col]; buc[c] = bu[col];
    }
    if (t < 128) {
        int gr = node0 + t;
        degs[t] = (gr < NNODES) ? degf[gr] : 0.f;
    }

    // quarter q: wave w stages its 512-u16 (ct=w) segment with ONE load.
    auto issue_q = [&](int q) {
        const unsigned short* src = wfrag + (size_t)q * 4096 + w * 512 + l * 8;
        unsigned short* dst = Q + (q % 5) * 4096 + w * 512;
        gload_lds16(src, dst, l);
    };
    issue_q(0); issue_q(1); issue_q(2); issue_q(3);

    f32x4 zz = { 0.f, 0.f, 0.f, 0.f };
    f32x4 acc1[2][4], acc2[2][4], acc3[2][4], accO[2][4];
#pragma unroll
    for (int f = 0; f < 2; ++f)
#pragma unroll
        for (int c = 0; c < 4; ++c) {
            acc1[f][c] = zz; acc2[f][c] = zz; acc3[f][c] = zz; accO[f][c] = zz;
        }

    auto bload = [&](int q5, int c) -> bf16x8 {
        return *(const bf16x8*)(Q + q5 * 4096 + (wc * 4 + c) * 512 + l * 8);
    };
    auto body_wn = [&](int kt, int q5) {      // Wn: X->acc1, S->acc2 (shared B)
        __builtin_amdgcn_s_setprio(1);
#pragma unroll
        for (int c = 0; c < 4; ++c) {
            bf16x8 b = bload(q5, c);
            acc1[0][c] = MFMA(aX[kt][0], b, acc1[0][c]);
            acc1[1][c] = MFMA(aX[kt][1], b, acc1[1][c]);
            acc2[0][c] = MFMA(aS[kt][0], b, acc2[0][c]);
            acc2[1][c] = MFMA(aS[kt][1], b, acc2[1][c]);
        }
        __builtin_amdgcn_s_setprio(0);
    };
    auto body_A = [&](int kt, int q5, bf16x8 (&A)[4][2], f32x4 (&acc)[2][4]) {
        __builtin_amdgcn_s_setprio(1);
#pragma unroll
        for (int c = 0; c < 4; ++c) {
            bf16x8 b = bload(q5, c);
            acc[0][c] = MFMA(A[kt][0], b, acc[0][c]);
            acc[1][c] = MFMA(A[kt][1], b, acc[1][c]);
        }
        __builtin_amdgcn_s_setprio(0);
    };
    auto body_wu = [&](int kt, int q5) {      // Wu*: G -> accO
        bf16x8 g0 = *(const bf16x8*)(Gs + (rb + l16) * 136 + kt * 32 + lg * 8);
        bf16x8 g1 = *(const bf16x8*)(Gs + (rb + 16 + l16) * 136 + kt * 32 + lg * 8);
        __builtin_amdgcn_s_setprio(1);
#pragma unroll
        for (int c = 0; c < 4; ++c) {
            bf16x8 b = bload(q5, c);
            accO[0][c] = MFMA(g0, b, accO[0][c]);
            accO[1][c] = MFMA(g1, b, accO[1][c]);
        }
        __builtin_amdgcn_s_setprio(0);
    };

    float dg[2][4];   // deg per accumulator row; filled after first barrier

    // degMode 0: v+bias; 1: v+deg*bias; 2: v as-is
    auto epi = [&](f32x4 (&acc)[2][4], const float* bias, int degMode) {
#pragma unroll
        for (int f = 0; f < 2; ++f)
#pragma unroll
            for (int c = 0; c < 4; ++c) {
                int col = (wc * 4 + c) * 16 + l16;
#pragma unroll
                for (int r = 0; r < 4; ++r) {
                    int row = rb + f * 16 + lg * 4 + r;
                    float v = acc[f][c][r];
                    if (degMode == 0) v += bias[c];
                    if (degMode == 1) v += dg[f][r] * bias[c];
                    Gs[row * 136 + col] = f2bf(gelu_fast(v));
                }
            }
    };
    auto fold3 = [&] {   // acc3 = deg[row] * (acc3 + be[col]); register-only
#pragma unroll
        for (int f = 0; f < 2; ++f)
#pragma unroll
            for (int c = 0; c < 4; ++c)
#pragma unroll
                for (int r = 0; r < 4; ++r)
                    acc3[f][c][r] = dg[f][r] * (acc3[f][c][r] + bec[c]);
    };

    // tiles: q0-3 Wn | q4-7 Wu0 | q8-11 We1 | q12-15 We2 | q16-19 Wu1 | q20-23 Wu2
    PREQ(0);
#pragma unroll
    for (int f = 0; f < 2; ++f)
#pragma unroll
        for (int r = 0; r < 4; ++r)
            dg[f][r] = degs[rb + f * 16 + lg * 4 + r];
    body_wn(0, 0);
    PREQ(1);  body_wn(1, 1);
    PREQ(2);  body_wn(2, 2);
    PREQ(3);  body_wn(3, 3);
    PREQ(4);  epi(acc1, bnc, 0); BARX(); body_wu(0, 4);
    PREQ(5);  body_wu(1, 0);
    PREQ(6);  body_wu(2, 1);
    PREQ(7);  body_wu(3, 2);
    PREQ(8);  body_A(0, 3, aX, acc3);
    PREQ(9);  body_A(1, 4, aX, acc3);
    PREQ(10); body_A(2, 0, aX, acc3);
    PREQ(11); body_A(3, 1, aX, acc3);
    fold3();
    PREQ(12); body_A(0, 2, aS, acc3);
    PREQ(13); body_A(1, 3, aS, acc3);
    PREQ(14); body_A(2, 4, aS, acc3);
    PREQ(15); body_A(3, 0, aS, acc3);
    PREQ(16); epi(acc2, bnc, 1); BARX(); body_wu(0, 1);
    PREQ(17); body_wu(1, 2);
    PREQ(18); body_wu(2, 3);
    PREQ(19); body_wu(3, 4);
    PREQ(20); epi(acc3, nullptr, 2); BARX(); body_wu(0, 0);
    PREQ(21); body_wu(1, 1);
    PREQ(22); body_wu(2, 2);
    PREQ(23); body_wu(3, 3);

    // ---- store ----
#pragma unroll
    for (int f = 0; f < 2; ++f)
#pragma unroll
        for (int c = 0; c < 4; ++c) {
            int col = (wc * 4 + c) * 16 + l16;
#pragma unroll
            for (int r = 0; r < 4; ++r) {
                int grow = node0 + rb + f * 16 + lg * 4 + r;
                if (grow < NNODES)
                    out[(size_t)grow * DD + col] = accO[f][c][r] + buc[c];
            }
        }
}

extern "C" void kernel_launch(void* const* d_in, const int* in_sizes, int n_in,
                              void* d_out, int out_size, void* d_ws, size_t ws_size,
                              hipStream_t stream) {
    const float* x  = (const float*)d_in[0];
    const int*   ei = (const int*)d_in[1];
    const float* Wn = (const float*)d_in[2];
    const float* bn = (const float*)d_in[3];
    const float* We = (const float*)d_in[4];
    const float* be = (const float*)d_in[5];
    const float* Wu = (const float*)d_in[6];
    const float* bu = (const float*)d_in[7];

    float* out = (float*)d_out;

    // ws layout: wfrag(196608) | degf | cnt | off | bsum | edst | xbf | Sbf
    unsigned short* wfrag = (unsigned short*)d_ws;
    float* degf = (float*)((char*)d_ws + 196608);
    int* cnt  = (int*)((char*)d_ws + 596608);
    int* off  = (int*)((char*)d_ws + 996608);
    int* bsum = (int*)((char*)d_ws + 1396608);
    int* edst = (int*)((char*)d_ws + 1398656);
    unsigned short* xbf = (unsigned short*)((char*)d_ws + 3798656);
    unsigned short* Sbf = (unsigned short*)((char*)d_ws + 29398656);

    int mode = 0;
    if (ws_size >= 29398656ULL + 25600000ULL) mode = 2;
    else if (ws_size >= 3798656ULL + 25600000ULL) mode = 1;

    int fblocks = (NNODES + 127) / 128;          // 782
    size_t lds_bytes = 5 * 4096 * 2 + 128 * 136 * 2 + 128 * 4;   // 76288
    int nb = (NNODES + SCAN_B - 1) / SCAN_B;     // 196
    int pblocks = (mode >= 1) ? (439 + NNODES * DD / 8 / 256) : 439;

    prep_k<<<pblocks, 256, 0, stream>>>(x, Wn, We, Wu, wfrag, cnt, xbf);
    hist_k<<<(NEDGES + 255) / 256, 256, 0, stream>>>(ei, cnt);
    scan_local<<<nb, SCAN_B, 0, stream>>>(cnt, off, bsum);
    scan_add2<<<(NNODES + 255) / 256, 256, 0, stream>>>(off, bsum, cnt, degf);
    fill_k<<<(NEDGES + 255) / 256, 256, 0, stream>>>(ei, off, edst);

    if (mode == 2) {
        agg2_k<true, true><<<NNODES / 4, 256, 0, stream>>>(off, edst, x, xbf, nullptr, Sbf);
        fused4_k<2><<<fblocks, 512, lds_bytes, stream>>>(x, xbf, nullptr, Sbf, degf, wfrag,
                                                         bn, be, bu, out);
    } else if (mode == 1) {
        agg2_k<true, false><<<NNODES / 4, 256, 0, stream>>>(off, edst, x, xbf, out, nullptr);
        fused4_k<1><<<fblocks, 512, lds_bytes, stream>>>(x, xbf, out, nullptr, degf, wfrag,
                                                         bn, be, bu, out);
    } else {
        agg2_k<false, false><<<NNODES / 4, 256, 0, stream>>>(off, edst, x, nullptr, out, nullptr);
        fused4_k<0><<<fblocks, 512, lds_bytes, stream>>>(x, nullptr, out, nullptr, degf, wfrag,
                                                         bn, be, bu, out);
    }
}

// Round 6
// 172.784 us; speedup vs baseline: 7.8274x; 1.1600x over previous
//
#include <hip/hip_runtime.h>
#include <hip/hip_bf16.h>
#include <math.h>

#define NNODES 100000
#define NEDGES 600000
#define DD 128
#define SCAN_B 512
#define NFRAGS 6250          // NNODES / 16
#define TGRID 256            // fusedT grid

typedef __attribute__((ext_vector_type(8))) short bf16x8;
typedef __attribute__((ext_vector_type(4))) float f32x4;
typedef __attribute__((ext_vector_type(4))) unsigned short u16x4;

static __device__ __forceinline__ unsigned short f2bf(float f) {
    __hip_bfloat16 h = __float2bfloat16(f);   // HW RNE cvt
    return __builtin_bit_cast(unsigned short, h);
}
static __device__ __forceinline__ float bf2f(unsigned short h) {
    unsigned u = ((unsigned)h) << 16;
    return __builtin_bit_cast(float, u);
}
// tanh-approx GELU via sigmoid, exp2-folded. |err| <= ~3e-3 (threshold 1.07).
static __device__ __forceinline__ float gelu_fast(float v) {
    float w = v * (-2.302203846f - 0.102943150f * v * v);
    return v / (1.0f + exp2f(w));
}

#if __has_builtin(__builtin_amdgcn_global_load_lds)
#define HAVE_GLDS 1
#else
#define HAVE_GLDS 0
#endif

static __device__ __forceinline__ void gload_lds16(const unsigned short* g, unsigned short* s, int lane) {
#if HAVE_GLDS
    (void)lane;
    __builtin_amdgcn_global_load_lds((const __attribute__((address_space(1))) void*)g,
                                     (__attribute__((address_space(3))) void*)s, 16, 0, 0);
#else
    *(bf16x8*)(s + lane * 8) = *(const bf16x8*)g;
#endif
}
static __device__ __forceinline__ void gload_lds4(const float* g, unsigned short* s, int lane) {
#if HAVE_GLDS
    (void)lane;
    __builtin_amdgcn_global_load_lds((const __attribute__((address_space(1))) void*)g,
                                     (__attribute__((address_space(3))) void*)s, 4, 0, 0);
#else
    *(float*)((char*)s + lane * 4) = *g;
#endif
}

#define MFMA(a, b, c) __builtin_amdgcn_mfma_f32_16x16x32_bf16(a, b, c, 0, 0, 0)
#define BARX() do { asm volatile("s_waitcnt lgkmcnt(0)" ::: "memory"); \
                    __builtin_amdgcn_s_barrier(); } while (0)

// ---------- prep: weights->frag-major bf16 | zero cnt | x->bf16 ----------
// LAYOUT 0 (fused4 fallback): [tile][kt][ct][lane][8], tiles [Wn,Wu0,We1,We2,Wu1,Wu2]
// LAYOUT 1 (fusedT):          frag g: Wn g<32 (nf=g>>2,kt=g&3) | We1 32..63 |
//                             We2 64..95 | Wu 96..191 (nf=gg/12, kt=gg%12)
template <int LAYOUT>
__global__ __launch_bounds__(256) void prep_k(const float* __restrict__ x,
                                              const float* __restrict__ Wn,
                                              const float* __restrict__ We,
                                              const float* __restrict__ Wu,
                                              unsigned short* __restrict__ wfrag,
                                              int* __restrict__ cnt,
                                              unsigned short* __restrict__ xb) {
    int b = blockIdx.x;
    int t = threadIdx.x;
    if (b < 48) {
        int tid = b * 256 + t;
        int l = tid & 63;
        const float* src;
        if constexpr (LAYOUT == 0) {
            int ct = (tid >> 6) & 7;
            int kt = (tid >> 9) & 3;
            int tile = tid >> 11;
            int n = ct * 16 + (l & 15);
            int k = kt * 32 + (l >> 4) * 8;
            switch (tile) {
                case 0:  src = Wn + (size_t)n * 128 + k;        break;
                case 1:  src = Wu + (size_t)n * 384 + k;        break;
                case 2:  src = We + (size_t)n * 256 + k;        break;
                case 3:  src = We + (size_t)n * 256 + 128 + k;  break;
                case 4:  src = Wu + (size_t)n * 384 + 128 + k;  break;
                default: src = Wu + (size_t)n * 384 + 256 + k;  break;
            }
        } else {
            int g = tid >> 6;
            int l16 = l & 15, lg8 = (l >> 4) * 8;
            if (g < 32)       { int nf = g >> 2,        kt = g & 3;
                                src = Wn + (size_t)(nf * 16 + l16) * 128 + kt * 32 + lg8; }
            else if (g < 64)  { int gg = g - 32; int nf = gg >> 2, kt = gg & 3;
                                src = We + (size_t)(nf * 16 + l16) * 256 + kt * 32 + lg8; }
            else if (g < 96)  { int gg = g - 64; int nf = gg >> 2, kt = gg & 3;
                                src = We + (size_t)(nf * 16 + l16) * 256 + 128 + kt * 32 + lg8; }
            else              { int gg = g - 96; int nf = gg / 12, kt = gg % 12;
                                src = Wu + (size_t)(nf * 16 + l16) * 384 + kt * 32 + lg8; }
        }
        unsigned short o[8];
#pragma unroll
        for (int j = 0; j < 8; ++j) o[j] = f2bf(src[j]);
        *(bf16x8*)(wfrag + (size_t)(b * 256 + t) * 8) = *(bf16x8*)o;
    } else if (b < 48 + 391) {
        int i = (b - 48) * 256 + t;
        if (i < NNODES) cnt[i] = 0;
    } else {
        int i = (b - 439) * 256 + t;   // < 1,600,000 exactly
        float4 v0 = *(const float4*)(x + (size_t)i * 8);
        float4 v1 = *(const float4*)(x + (size_t)i * 8 + 4);
        unsigned short o[8] = { f2bf(v0.x), f2bf(v0.y), f2bf(v0.z), f2bf(v0.w),
                                f2bf(v1.x), f2bf(v1.y), f2bf(v1.z), f2bf(v1.w) };
        *(bf16x8*)(xb + (size_t)i * 8) = *(bf16x8*)o;
    }
}

// ---------------- CSR build ----------------
__global__ __launch_bounds__(256) void hist_k(const int* __restrict__ ei, int* __restrict__ cnt) {
    int e = blockIdx.x * 256 + threadIdx.x;
    if (e < NEDGES) atomicAdd(&cnt[ei[e]], 1);
}

__global__ __launch_bounds__(SCAN_B) void scan_local(const int* __restrict__ cnt,
                                                     int* __restrict__ off,
                                                     int* __restrict__ bsum) {
    __shared__ int sh[SCAN_B];
    int i = blockIdx.x * SCAN_B + threadIdx.x;
    int v = (i < NNODES) ? cnt[i] : 0;
    sh[threadIdx.x] = v;
    __syncthreads();
    for (int d = 1; d < SCAN_B; d <<= 1) {
        int t = (threadIdx.x >= d) ? sh[threadIdx.x - d] : 0;
        __syncthreads();
        sh[threadIdx.x] += t;
        __syncthreads();
    }
    if (i < NNODES) off[i] = sh[threadIdx.x] - v;
    if (threadIdx.x == SCAN_B - 1) bsum[blockIdx.x] = sh[threadIdx.x];
}

__global__ __launch_bounds__(256) void scan_add2(int* __restrict__ off,
                                                 const int* __restrict__ bsum,
                                                 const int* __restrict__ cnt,
                                                 float* __restrict__ degf) {
    __shared__ int sp;
    int K = blockIdx.x >> 1;
    int t = threadIdx.x;
    if (t < 64) {
        int s = 0;
        for (int j = t; j < K; j += 64) s += bsum[j];
#pragma unroll
        for (int d = 32; d; d >>= 1) s += __shfl_down(s, d, 64);
        if (t == 0) sp = s;
    }
    __syncthreads();
    int i = blockIdx.x * 256 + t;
    if (i < NNODES) {
        off[i] += sp;
        degf[i] = (float)cnt[i];
    }
}

__global__ __launch_bounds__(256) void fill_k(const int* __restrict__ ei,
                                              int* __restrict__ off,
                                              int* __restrict__ edst) {
    int e = blockIdx.x * 256 + threadIdx.x;
    if (e >= NEDGES) return;
    int s = ei[e], d = ei[NEDGES + e];
    int pos = atomicAdd(&off[s], 1);
    edst[pos] = d;
}

// ---------------- aggregate S[v] = sum x[dst] ----------------
template <bool IN_BF, bool OUT_BF>
__global__ __launch_bounds__(256) void agg2_k(const int* __restrict__ off,
                                              const int* __restrict__ edst,
                                              const float* __restrict__ xf,
                                              const unsigned short* __restrict__ xb,
                                              float* Sf, unsigned short* Sb) {
    int node = (blockIdx.x * 256 + threadIdx.x) >> 6;
    if (node >= NNODES) return;
    int l = threadIdx.x & 63;
    int es = l >> 4;
    int cg = l & 15;
    int end = off[node];
    int beg = node ? off[node - 1] : 0;
    float acc[8] = {0.f, 0.f, 0.f, 0.f, 0.f, 0.f, 0.f, 0.f};
    for (int e = beg + es; e < end; e += 4) {
        int d = edst[e];
        if constexpr (IN_BF) {
            bf16x8 v = *(const bf16x8*)(xb + (size_t)d * DD + cg * 8);
#pragma unroll
            for (int j = 0; j < 8; ++j) acc[j] += bf2f((unsigned short)v[j]);
        } else {
            const float* p = xf + (size_t)d * DD + cg * 8;
            float4 v0 = *(const float4*)(p);
            float4 v1 = *(const float4*)(p + 4);
            acc[0] += v0.x; acc[1] += v0.y; acc[2] += v0.z; acc[3] += v0.w;
            acc[4] += v1.x; acc[5] += v1.y; acc[6] += v1.z; acc[7] += v1.w;
        }
    }
#pragma unroll
    for (int j = 0; j < 8; ++j) {
        acc[j] += __shfl_xor(acc[j], 16, 64);
        acc[j] += __shfl_xor(acc[j], 32, 64);
    }
    if (es == 0) {
        if constexpr (OUT_BF) {
            unsigned short o[8];
#pragma unroll
            for (int j = 0; j < 8; ++j) o[j] = f2bf(acc[j]);
            *(bf16x8*)(Sb + (size_t)node * DD + cg * 8) = *(bf16x8*)o;
        } else {
            float4 r0 = { acc[0], acc[1], acc[2], acc[3] };
            float4 r1 = { acc[4], acc[5], acc[6], acc[7] };
            *(float4*)(Sf + (size_t)node * DD + cg * 8) = r0;
            *(float4*)(Sf + (size_t)node * DD + cg * 8 + 4) = r1;
        }
    }
}

// ============ fusedT: transposed GEMM, weights register-resident ============
// preT = W @ [x|S]^T per 16-node frag; lane l16 = node; regs = pre/out cols.
// Wave w owns n-slice [16w,16w+16) of g0/g1/g2 and out-col slice [16w,16w+16).
// out[v] = gelu(x@Wn.T+bn)@Wu0.T + gelu(S@Wn.T+deg*bn)@Wu1.T
//        + gelu(deg*(x@We1.T+be)+S@We2.T)@Wu2.T + bu
__global__ __launch_bounds__(512, 2) void fusedT_k(const unsigned short* __restrict__ xb,
                                                   const unsigned short* __restrict__ Sb,
                                                   const float* __restrict__ degf,
                                                   const unsigned short* __restrict__ wfrag,
                                                   const float* __restrict__ bn,
                                                   const float* __restrict__ be,
                                                   const float* __restrict__ bu,
                                                   float* __restrict__ out) {
    // XS buf: 8KB x|S rows (XOR-swizzled content) + 256B deg = 8448B, x3 bufs
    __shared__ __align__(16) unsigned short XS[3][4224];
    __shared__ __align__(16) unsigned short Gs[2][6144];   // 16 rows x 768B, swizzled

    const int t = threadIdx.x;
    const int w = t >> 6;
    const int l = t & 63;
    const int l16 = l & 15;
    const int lg = l >> 4;
    const int sw = (l16 & 7) << 4;    // row-XOR swizzle

    // ---- persistent weights: 24 frags = 96 VGPR ----
    bf16x8 wn[4], we1[4], we2[4], wu[12];
#pragma unroll
    for (int kt = 0; kt < 4; ++kt) {
        wn[kt]  = *(const bf16x8*)(wfrag + (size_t)((w * 4 + kt) << 9) + l * 8);
        we1[kt] = *(const bf16x8*)(wfrag + (size_t)((32 + w * 4 + kt) << 9) + l * 8);
        we2[kt] = *(const bf16x8*)(wfrag + (size_t)((64 + w * 4 + kt) << 9) + l * 8);
    }
#pragma unroll
    for (int j = 0; j < 12; ++j)
        wu[j] = *(const bf16x8*)(wfrag + (size_t)((96 + w * 12 + j) << 9) + l * 8);
    f32x4 bnr = *(const f32x4*)(bn + w * 16 + lg * 4);
    f32x4 ber = *(const f32x4*)(be + w * 16 + lg * 4);
    f32x4 bur = *(const f32x4*)(bu + w * 16 + lg * 4);

    const int f0 = blockIdx.x;
    const int nIters = (NFRAGS - f0 + TGRID - 1) / TGRID;   // 24 or 25

    // stage frag f's 16 x-rows + 16 S-rows (8KB) + deg (256B) into XS[buf].
    // content pre-permuted so reads use byte ^ ((row&7)<<4).
    auto issueB = [&](int f, int buf) {
        int fc = (f < NFRAGS) ? f : (NFRAGS - 1);
        int p  = (w << 10) + (l << 4);          // linear byte pos in 8KB
        int po = p & 4095;
        int q  = po ^ (((po >> 8) & 7) << 4);   // pre-permuted source offset
        const unsigned short* base = (w < 4) ? xb : Sb;
        const unsigned short* src = base + (size_t)fc * 2048 + (q >> 1);
        unsigned short* dst = &XS[buf][(size_t)w << 9];    // wave-uniform base
        gload_lds16(src, dst, l);
        gload_lds4(degf + fc * 16 + l16, &XS[buf][4096], l);
    };

    auto gemm1_epi = [&](const unsigned short* xs, unsigned short* gsw) {
        const char* xsb = (const char*)xs;
        bf16x8 bx[4], bs[4];
#pragma unroll
        for (int kt = 0; kt < 4; ++kt) {
            int po = (l16 << 8) + (kt << 6) + (lg << 4);
            bx[kt] = *(const bf16x8*)(xsb + (po ^ sw));
            bs[kt] = *(const bf16x8*)(xsb + 4096 + (po ^ sw));
        }
        float dg = *(const float*)(xsb + 8192 + l16 * 4);
        f32x4 a0 = {0.f,0.f,0.f,0.f}, a1 = a0, a2 = a0, a3 = a0;
        __builtin_amdgcn_s_setprio(1);
#pragma unroll
        for (int kt = 0; kt < 4; ++kt) {
            a0 = MFMA(wn[kt],  bx[kt], a0);
            a1 = MFMA(wn[kt],  bs[kt], a1);
            a2 = MFMA(we1[kt], bx[kt], a2);
            a3 = MFMA(we2[kt], bs[kt], a3);
        }
        __builtin_amdgcn_s_setprio(0);
        u16x4 g0, g1, g2;
#pragma unroll
        for (int r = 0; r < 4; ++r) {
            g0[r] = f2bf(gelu_fast(a0[r] + bnr[r]));
            g1[r] = f2bf(gelu_fast(a1[r] + dg * bnr[r]));
            g2[r] = f2bf(gelu_fast(dg * (a2[r] + ber[r]) + a3[r]));
        }
        char* gb = (char*)gsw;
        int cb = w * 32 + lg * 8;                 // col byte of this lane's 4 cols
        *(u16x4*)(gb + ((l16 * 768 + cb)       ^ sw)) = g0;
        *(u16x4*)(gb + ((l16 * 768 + 256 + cb) ^ sw)) = g1;
        *(u16x4*)(gb + ((l16 * 768 + 512 + cb) ^ sw)) = g2;
    };

    auto gemm2_store = [&](int f, const unsigned short* gsr) {
        const char* gb = (const char*)gsr;
        f32x4 o = {0.f, 0.f, 0.f, 0.f};
        __builtin_amdgcn_s_setprio(1);
#pragma unroll
        for (int j = 0; j < 12; ++j) {
            bf16x8 g = *(const bf16x8*)(gb + ((l16 * 768 + j * 64 + lg * 16) ^ sw));
            o = MFMA(wu[j], g, o);
        }
        __builtin_amdgcn_s_setprio(0);
        int v = f * 16 + l16;
        float4 st = { o[0] + bur[0], o[1] + bur[1], o[2] + bur[2], o[3] + bur[3] };
        *(float4*)(out + (size_t)v * DD + w * 16 + lg * 4) = st;
    };

    // ---- pipeline ----
    issueB(f0, 0);
    issueB(f0 + TGRID, 1);

    // i = 0
    issueB(f0 + 2 * TGRID, 2);
    asm volatile("s_waitcnt vmcnt(4)" ::: "memory");   // B(0) complete
    BARX();
    gemm1_epi(&XS[0][0], &Gs[0][0]);
    BARX();

    // i = 1
    gemm2_store(f0, &Gs[0][0]);
    issueB(f0 + 3 * TGRID, 0);
    asm volatile("s_waitcnt vmcnt(8)" ::: "memory");   // B(1) complete
    BARX();
    gemm1_epi(&XS[1][0], &Gs[1][0]);
    BARX();

    for (int i = 2; i < nIters; ++i) {
        gemm2_store(f0 + (i - 1) * TGRID, &Gs[(i - 1) & 1][0]);
        issueB(f0 + (i + 2) * TGRID, (i + 2) % 3);
        asm volatile("s_waitcnt vmcnt(12)" ::: "memory");  // B(i) complete
        BARX();
        gemm1_epi(&XS[i % 3][0], &Gs[i & 1][0]);
        BARX();
    }
    gemm2_store(f0 + (nIters - 1) * TGRID, &Gs[(nIters - 1) & 1][0]);
}

// =============== fallback fused4_k (modes 0/1, unchanged from R5) ===============
#define PREQ(q) do { \
    if ((q) <= 20)      asm volatile("s_waitcnt vmcnt(3)" ::: "memory"); \
    else if ((q) == 21) asm volatile("s_waitcnt vmcnt(2)" ::: "memory"); \
    else if ((q) == 22) asm volatile("s_waitcnt vmcnt(1)" ::: "memory"); \
    else                asm volatile("s_waitcnt vmcnt(0)" ::: "memory"); \
    asm volatile("s_waitcnt lgkmcnt(0)" ::: "memory"); \
    __builtin_amdgcn_s_barrier(); \
    if ((q) + 4 < 24) issue_q((q) + 4); } while (0)

template <int MODE>
__global__ __launch_bounds__(512) void fused4_k(const float* __restrict__ xf,
                                                const unsigned short* __restrict__ xb,
                                                const float* Sf,
                                                const float* __restrict__ degf,
                                                const unsigned short* __restrict__ wfrag,
                                                const float* __restrict__ bn,
                                                const float* __restrict__ be,
                                                const float* __restrict__ bu,
                                                float* out) {
    extern __shared__ char smem[];
    unsigned short* Q  = (unsigned short*)smem;
    unsigned short* Gs = Q + 5 * 4096;
    float* degs = (float*)(Gs + 128 * 136);

    const int t = threadIdx.x;
    const int w = t >> 6;
    const int l = t & 63;
    const int wc = w & 1;
    const int rb = (w >> 1) * 32;
    const int l16 = l & 15;
    const int lg = l >> 4;
    const int node0 = blockIdx.x * 128;

    int r0 = node0 + rb + l16;      if (r0 > NNODES - 1) r0 = NNODES - 1;
    int r1 = node0 + rb + 16 + l16; if (r1 > NNODES - 1) r1 = NNODES - 1;

    auto loadA_bf = [&](const unsigned short* rowp, bf16x8 (&A)[4][2], int f) {
#pragma unroll
        for (int kt = 0; kt < 4; ++kt)
            A[kt][f] = *(const bf16x8*)(rowp + kt * 32 + lg * 8);
    };
    auto loadA_f32 = [&](const float* rowp, bf16x8 (&A)[4][2], int f) {
#pragma unroll
        for (int kt = 0; kt < 4; ++kt) {
            const float* p = rowp + kt * 32 + lg * 8;
            float4 v0 = *(const float4*)(p);
            float4 v1 = *(const float4*)(p + 4);
            bf16x8 a;
            a[0] = (short)f2bf(v0.x); a[1] = (short)f2bf(v0.y);
            a[2] = (short)f2bf(v0.z); a[3] = (short)f2bf(v0.w);
            a[4] = (short)f2bf(v1.x); a[5] = (short)f2bf(v1.y);
            a[6] = (short)f2bf(v1.z); a[7] = (short)f2bf(v1.w);
            A[kt][f] = a;
        }
    };

    bf16x8 aX[4][2], aS[4][2];
    if constexpr (MODE >= 1) {
        loadA_bf(xb + (size_t)r0 * DD, aX, 0);
        loadA_bf(xb + (size_t)r1 * DD, aX, 1);
    } else {
        loadA_f32(xf + (size_t)r0 * DD, aX, 0);
        loadA_f32(xf + (size_t)r1 * DD, aX, 1);
    }
    loadA_f32(Sf + (size_t)r0 * DD, aS, 0);
    loadA_f32(Sf + (size_t)r1 * DD, aS, 1);
    float bnc[4], bec[4], buc[4];
#pragma unroll
    for (int c = 0; c < 4; ++c) {
        int col = (wc * 4 + c) * 16 + l16;
        bnc[c] = bn[col]; bec[c] = be[col]; buc[c] = bu[col];
    }
    if (t < 128) {
        int gr = node0 + t;
        degs[t] = (gr < NNODES) ? degf[gr] : 0.f;
    }

    auto issue_q = [&](int q) {
        const unsigned short* src = wfrag + (size_t)q * 4096 + w * 512 + l * 8;
        unsigned short* dst = Q + (q % 5) * 4096 + w * 512;
        gload_lds16(src, dst, l);
    };
    issue_q(0); issue_q(1); issue_q(2); issue_q(3);

    f32x4 zz = { 0.f, 0.f, 0.f, 0.f };
    f32x4 acc1[2][4], acc2[2][4], acc3[2][4], accO[2][4];
#pragma unroll
    for (int f = 0; f < 2; ++f)
#pragma unroll
        for (int c = 0; c < 4; ++c) {
            acc1[f][c] = zz; acc2[f][c] = zz; acc3[f][c] = zz; accO[f][c] = zz;
        }

    auto bload = [&](int q5, int c) -> bf16x8 {
        return *(const bf16x8*)(Q + q5 * 4096 + (wc * 4 + c) * 512 + l * 8);
    };
    auto body_wn = [&](int kt, int q5) {
        __builtin_amdgcn_s_setprio(1);
#pragma unroll
        for (int c = 0; c < 4; ++c) {
            bf16x8 b = bload(q5, c);
            acc1[0][c] = MFMA(aX[kt][0], b, acc1[0][c]);
            acc1[1][c] = MFMA(aX[kt][1], b, acc1[1][c]);
            acc2[0][c] = MFMA(aS[kt][0], b, acc2[0][c]);
            acc2[1][c] = MFMA(aS[kt][1], b, acc2[1][c]);
        }
        __builtin_amdgcn_s_setprio(0);
    };
    auto body_A = [&](int kt, int q5, bf16x8 (&A)[4][2], f32x4 (&acc)[2][4]) {
        __builtin_amdgcn_s_setprio(1);
#pragma unroll
        for (int c = 0; c < 4; ++c) {
            bf16x8 b = bload(q5, c);
            acc[0][c] = MFMA(A[kt][0], b, acc[0][c]);
            acc[1][c] = MFMA(A[kt][1], b, acc[1][c]);
        }
        __builtin_amdgcn_s_setprio(0);
    };
    auto body_wu = [&](int kt, int q5) {
        bf16x8 g0 = *(const bf16x8*)(Gs + (rb + l16) * 136 + kt * 32 + lg * 8);
        bf16x8 g1 = *(const bf16x8*)(Gs + (rb + 16 + l16) * 136 + kt * 32 + lg * 8);
        __builtin_amdgcn_s_setprio(1);
#pragma unroll
        for (int c = 0; c < 4; ++c) {
            bf16x8 b = bload(q5, c);
            accO[0][c] = MFMA(g0, b, accO[0][c]);
            accO[1][c] = MFMA(g1, b, accO[1][c]);
        }
        __builtin_amdgcn_s_setprio(0);
    };

    float dg[2][4];
    auto epi = [&](f32x4 (&acc)[2][4], const float* bias, int degMode) {
#pragma unroll
        for (int f = 0; f < 2; ++f)
#pragma unroll
            for (int c = 0; c < 4; ++c) {
                int col = (wc * 4 + c) * 16 + l16;
#pragma unroll
                for (int r = 0; r < 4; ++r) {
                    int row = rb + f * 16 + lg * 4 + r;
                    float v = acc[f][c][r];
                    if (degMode == 0) v += bias[c];
                    if (degMode == 1) v += dg[f][r] * bias[c];
                    Gs[row * 136 + col] = f2bf(gelu_fast(v));
                }
            }
    };
    auto fold3 = [&] {
#pragma unroll
        for (int f = 0; f < 2; ++f)
#pragma unroll
            for (int c = 0; c < 4; ++c)
#pragma unroll
                for (int r = 0; r < 4; ++r)
                    acc3[f][c][r] = dg[f][r] * (acc3[f][c][r] + bec[c]);
    };

    PREQ(0);
#pragma unroll
    for (int f = 0; f < 2; ++f)
#pragma unroll
        for (int r = 0; r < 4; ++r)
            dg[f][r] = degs[rb + f * 16 + lg * 4 + r];
    body_wn(0, 0);
    PREQ(1);  body_wn(1, 1);
    PREQ(2);  body_wn(2, 2);
    PREQ(3);  body_wn(3, 3);
    PREQ(4);  epi(acc1, bnc, 0); BARX(); body_wu(0, 4);
    PREQ(5);  body_wu(1, 0);
    PREQ(6);  body_wu(2, 1);
    PREQ(7);  body_wu(3, 2);
    PREQ(8);  body_A(0, 3, aX, acc3);
    PREQ(9);  body_A(1, 4, aX, acc3);
    PREQ(10); body_A(2, 0, aX, acc3);
    PREQ(11); body_A(3, 1, aX, acc3);
    fold3();
    PREQ(12); body_A(0, 2, aS, acc3);
    PREQ(13); body_A(1, 3, aS, acc3);
    PREQ(14); body_A(2, 4, aS, acc3);
    PREQ(15); body_A(3, 0, aS, acc3);
    PREQ(16); epi(acc2, bnc, 1); BARX(); body_wu(0, 1);
    PREQ(17); body_wu(1, 2);
    PREQ(18); body_wu(2, 3);
    PREQ(19); body_wu(3, 4);
    PREQ(20); epi(acc3, nullptr, 2); BARX(); body_wu(0, 0);
    PREQ(21); body_wu(1, 1);
    PREQ(22); body_wu(2, 2);
    PREQ(23); body_wu(3, 3);

#pragma unroll
    for (int f = 0; f < 2; ++f)
#pragma unroll
        for (int c = 0; c < 4; ++c) {
            int col = (wc * 4 + c) * 16 + l16;
#pragma unroll
            for (int r = 0; r < 4; ++r) {
                int grow = node0 + rb + f * 16 + lg * 4 + r;
                if (grow < NNODES)
                    out[(size_t)grow * DD + col] = accO[f][c][r] + buc[c];
            }
        }
}

extern "C" void kernel_launch(void* const* d_in, const int* in_sizes, int n_in,
                              void* d_out, int out_size, void* d_ws, size_t ws_size,
                              hipStream_t stream) {
    const float* x  = (const float*)d_in[0];
    const int*   ei = (const int*)d_in[1];
    const float* Wn = (const float*)d_in[2];
    const float* bn = (const float*)d_in[3];
    const float* We = (const float*)d_in[4];
    const float* be = (const float*)d_in[5];
    const float* Wu = (const float*)d_in[6];
    const float* bu = (const float*)d_in[7];

    float* out = (float*)d_out;

    // ws layout: wfrag(196608) | degf | cnt | off | bsum | edst | xbf | Sbf
    unsigned short* wfrag = (unsigned short*)d_ws;
    float* degf = (float*)((char*)d_ws + 196608);
    int* cnt  = (int*)((char*)d_ws + 596608);
    int* off  = (int*)((char*)d_ws + 996608);
    int* bsum = (int*)((char*)d_ws + 1396608);
    int* edst = (int*)((char*)d_ws + 1398656);
    unsigned short* xbf = (unsigned short*)((char*)d_ws + 3798656);
    unsigned short* Sbf = (unsigned short*)((char*)d_ws + 29398656);

    int mode = 0;
    if (ws_size >= 29398656ULL + 25600000ULL) mode = 2;
    else if (ws_size >= 3798656ULL + 25600000ULL) mode = 1;

    int nb = (NNODES + SCAN_B - 1) / SCAN_B;     // 196
    int pblocks = (mode >= 1) ? (439 + NNODES * DD / 8 / 256) : 439;

    if (mode == 2) {
        prep_k<1><<<pblocks, 256, 0, stream>>>(x, Wn, We, Wu, wfrag, cnt, xbf);
        hist_k<<<(NEDGES + 255) / 256, 256, 0, stream>>>(ei, cnt);
        scan_local<<<nb, SCAN_B, 0, stream>>>(cnt, off, bsum);
        scan_add2<<<(NNODES + 255) / 256, 256, 0, stream>>>(off, bsum, cnt, degf);
        fill_k<<<(NEDGES + 255) / 256, 256, 0, stream>>>(ei, off, edst);
        agg2_k<true, true><<<NNODES / 4, 256, 0, stream>>>(off, edst, x, xbf, nullptr, Sbf);
        fusedT_k<<<TGRID, 512, 0, stream>>>(xbf, Sbf, degf, wfrag, bn, be, bu, out);
    } else {
        prep_k<0><<<pblocks, 256, 0, stream>>>(x, Wn, We, Wu, wfrag, cnt, xbf);
        hist_k<<<(NEDGES + 255) / 256, 256, 0, stream>>>(ei, cnt);
        scan_local<<<nb, SCAN_B, 0, stream>>>(cnt, off, bsum);
        scan_add2<<<(NNODES + 255) / 256, 256, 0, stream>>>(off, bsum, cnt, degf);
        fill_k<<<(NEDGES + 255) / 256, 256, 0, stream>>>(ei, off, edst);
        int fblocks = (NNODES + 127) / 128;
        size_t lds_bytes = 5 * 4096 * 2 + 128 * 136 * 2 + 128 * 4;
        if (mode == 1) {
            agg2_k<true, false><<<NNODES / 4, 256, 0, stream>>>(off, edst, x, xbf, out, nullptr);
            fused4_k<1><<<fblocks, 512, lds_bytes, stream>>>(x, xbf, out, degf, wfrag,
                                                             bn, be, bu, out);
        } else {
            agg2_k<false, false><<<NNODES / 4, 256, 0, stream>>>(off, edst, x, nullptr, out, nullptr);
            fused4_k<0><<<fblocks, 512, lds_bytes, stream>>>(x, nullptr, out, degf, wfrag,
                                                             bn, be, bu, out);
        }
    }
}